// Round 1
// 524.080 us; speedup vs baseline: 1.1408x; 1.1408x over previous
//
#include <hip/hip_runtime.h>
#include <math.h>
#include <stdint.h>

// Problem constants (match reference)
#define Bb 2
#define Lq 2048
#define Dm 2048
#define Hh 16
#define DH 128
#define DREL 64
#define KTOP 512   // 0.25 * L

#define NEG_INF (-__builtin_huge_valf())

typedef __attribute__((ext_vector_type(8))) short bf16x8;   // 8 bf16 (4 VGPRs)
typedef __attribute__((ext_vector_type(4))) float f32x4;

static __device__ __forceinline__ unsigned short f2bf(float f) {
  unsigned int u = __float_as_uint(f);
  u += 0x7fffu + ((u >> 16) & 1u);   // RNE
  return (unsigned short)(u >> 16);
}

// async global->LDS, 16B per lane; LDS dest = wave-uniform base + lane*16
static __device__ __forceinline__ void gload16(const void* g, void* lds) {
  __builtin_amdgcn_global_load_lds(
      (const __attribute__((address_space(1))) uint32_t*)(uintptr_t)g,
      (__attribute__((address_space(3))) uint32_t*)(uint32_t)(uintptr_t)lds,
      16, 0, 0);
}

// ---------------------------------------------------------------------------
// fp32 -> bf16 elementwise with optional scale (n8 = n/8)
// ---------------------------------------------------------------------------
__global__ __launch_bounds__(256) void conv_bf16(const float* __restrict__ in,
                                                 unsigned short* __restrict__ out,
                                                 int n8, float scale) {
  const int i = blockIdx.x * 256 + threadIdx.x;
  if (i >= n8) return;
  const float4 f0 = ((const float4*)in)[2 * i];
  const float4 f1 = ((const float4*)in)[2 * i + 1];
  bf16x8 o;
  o[0] = (short)f2bf(f0.x * scale); o[1] = (short)f2bf(f0.y * scale);
  o[2] = (short)f2bf(f0.z * scale); o[3] = (short)f2bf(f0.w * scale);
  o[4] = (short)f2bf(f1.x * scale); o[5] = (short)f2bf(f1.y * scale);
  o[6] = (short)f2bf(f1.z * scale); o[7] = (short)f2bf(f1.w * scale);
  *(bf16x8*)(out + 8 * (size_t)i) = o;
}

// ---------------------------------------------------------------------------
// bf16 MFMA GEMM (m97 structure): C[M,N] = A[M,K] @ W[N,K]^T, fp32 accum.
// ---------------------------------------------------------------------------
template <bool BF16OUT>
__global__ __launch_bounds__(256) void gemm_bf(const unsigned short* __restrict__ A,
                                               const unsigned short* __restrict__ W,
                                               void* __restrict__ Cv,
                                               int M, int N, int Kd) {
  __shared__ unsigned short As[128][32];
  __shared__ unsigned short Bs[128][32];
  const int tid = threadIdx.x;
  const int w = tid >> 6;
  const int lane = tid & 63;
  const int l15 = lane & 15;
  const int quad = lane >> 4;
  const int wm = w >> 1, wn = w & 1;
  const int m0 = blockIdx.y * 128, n0 = blockIdx.x * 128;

  const int srow = lane >> 2;        // 0..15
  const int scol = (lane & 3) * 8;   // element col (8 bf16 = 16B)

  const unsigned short* aR0 = A + (size_t)(m0 + w * 32 + srow) * Kd + scol;
  const unsigned short* aR1 = aR0 + (size_t)16 * Kd;
  const unsigned short* bR0 = W + (size_t)(n0 + w * 32 + srow) * Kd + scol;
  const unsigned short* bR1 = bR0 + (size_t)16 * Kd;

  f32x4 acc[4][4];
#pragma unroll
  for (int i = 0; i < 4; ++i)
#pragma unroll
    for (int j = 0; j < 4; ++j) acc[i][j] = (f32x4){0.f, 0.f, 0.f, 0.f};

  for (int k0 = 0; k0 < Kd; k0 += 32) {
    gload16(aR0 + k0, &As[w * 32][0]);
    gload16(aR1 + k0, &As[w * 32 + 16][0]);
    gload16(bR0 + k0, &Bs[w * 32][0]);
    gload16(bR1 + k0, &Bs[w * 32 + 16][0]);
    __syncthreads();

    bf16x8 af[4], bfr[4];
#pragma unroll
    for (int im = 0; im < 4; ++im)
      af[im] = *(const bf16x8*)&As[wm * 64 + im * 16 + l15][quad * 8];
#pragma unroll
    for (int in = 0; in < 4; ++in)
      bfr[in] = *(const bf16x8*)&Bs[wn * 64 + in * 16 + l15][quad * 8];
#pragma unroll
    for (int im = 0; im < 4; ++im)
#pragma unroll
      for (int in = 0; in < 4; ++in)
        acc[im][in] = __builtin_amdgcn_mfma_f32_16x16x32_bf16(af[im], bfr[in], acc[im][in], 0, 0, 0);
    __syncthreads();
  }

#pragma unroll
  for (int im = 0; im < 4; ++im) {
#pragma unroll
    for (int in = 0; in < 4; ++in) {
      const int col = n0 + wn * 64 + in * 16 + l15;
#pragma unroll
      for (int r = 0; r < 4; ++r) {
        const int row = m0 + wm * 64 + im * 16 + quad * 4 + r;
        if (BF16OUT)
          ((unsigned short*)Cv)[(size_t)row * N + col] = f2bf(acc[im][in][r]);
        else
          ((float*)Cv)[(size_t)row * N + col] = acc[im][in][r];
      }
    }
  }
}

// ---------------------------------------------------------------------------
// Split-K fp32 rel projection: part[ks][128 rows][64 cols] over k-slice of 256.
// ---------------------------------------------------------------------------
#define RKS 8
__global__ __launch_bounds__(256) void relproj(const float* __restrict__ A,
                                               const float* __restrict__ W,
                                               float* __restrict__ part, int M) {
  __shared__ float As[16][128];
  __shared__ float Bs[16][64];
  const int ks = blockIdx.x;
  const int m0 = blockIdx.y * 128;
  const int tid = threadIdx.x;
  const int tx = tid & 15;   // col group (4 cols)
  const int ty = tid >> 4;   // row group (8 rows)
  const int lr = tid >> 1, lk = (tid & 1) * 8;
  const int wr = tid >> 2, wk = (tid & 3) * 4;

  float acc[8][4];
#pragma unroll
  for (int i = 0; i < 8; ++i)
#pragma unroll
    for (int j = 0; j < 4; ++j) acc[i][j] = 0.f;

  const int k00 = ks * (Dm / RKS);
  for (int k0 = k00; k0 < k00 + Dm / RKS; k0 += 16) {
    {
      const float* ap = A + (size_t)(m0 + lr) * Dm + k0 + lk;
      float4 a0 = *(const float4*)(ap);
      float4 a1 = *(const float4*)(ap + 4);
      As[lk + 0][lr] = a0.x; As[lk + 1][lr] = a0.y;
      As[lk + 2][lr] = a0.z; As[lk + 3][lr] = a0.w;
      As[lk + 4][lr] = a1.x; As[lk + 5][lr] = a1.y;
      As[lk + 6][lr] = a1.z; As[lk + 7][lr] = a1.w;
    }
    {
      const float* bp = W + (size_t)wr * Dm + k0 + wk;
      float4 b0 = *(const float4*)(bp);
      Bs[wk + 0][wr] = b0.x; Bs[wk + 1][wr] = b0.y;
      Bs[wk + 2][wr] = b0.z; Bs[wk + 3][wr] = b0.w;
    }
    __syncthreads();
#pragma unroll
    for (int kk = 0; kk < 16; ++kk) {
      float af[8], bf[4];
#pragma unroll
      for (int i = 0; i < 8; ++i) af[i] = As[kk][ty * 8 + i];
#pragma unroll
      for (int j = 0; j < 4; ++j) bf[j] = Bs[kk][tx * 4 + j];
#pragma unroll
      for (int i = 0; i < 8; ++i)
#pragma unroll
        for (int j = 0; j < 4; ++j) acc[i][j] += af[i] * bf[j];
    }
    __syncthreads();
  }

#pragma unroll
  for (int i = 0; i < 8; ++i) {
    float* pp = part + ((size_t)ks * M + m0 + ty * 8 + i) * DREL + tx * 4;
    *(float4*)pp = make_float4(acc[i][0], acc[i][1], acc[i][2], acc[i][3]);
  }
}

__global__ __launch_bounds__(256) void relreduce(const float* __restrict__ pq,
                                                 const float* __restrict__ pk,
                                                 float* __restrict__ qrel,
                                                 float* __restrict__ krel, int n4) {
  const int i = blockIdx.x * 256 + threadIdx.x;
  if (i >= n4) return;
  float4 sq = make_float4(0, 0, 0, 0), sk = sq;
  for (int s = 0; s < RKS; ++s) {
    float4 a = ((const float4*)pq)[(size_t)s * n4 + i];
    float4 b = ((const float4*)pk)[(size_t)s * n4 + i];
    sq.x += a.x; sq.y += a.y; sq.z += a.z; sq.w += a.w;
    sk.x += b.x; sk.y += b.y; sk.z += b.z; sk.w += b.w;
  }
  ((float4*)qrel)[i] = sq;
  ((float4*)krel)[i] = sk;
}

// ---------------------------------------------------------------------------
// Dense triangular rel-score GEMM: S[b][q][j] = (qrel[b,q,:]·krel[b,j,:])*DREL^-0.5
// ---------------------------------------------------------------------------
__global__ __launch_bounds__(256) void relscore(const float* __restrict__ qrel,
                                                const float* __restrict__ krel,
                                                float* __restrict__ S) {
  const int jt = blockIdx.x, qt = blockIdx.y, b = blockIdx.z;
  if (jt > qt) return;
  __shared__ float As[16][128];
  __shared__ float Bs[16][128];
  const int tid = threadIdx.x;
  const int q0 = qt * 128, j0 = jt * 128;
  const int tx = tid & 15, ty = tid >> 4;
  const int lr = tid >> 1, lk = (tid & 1) * 8;
  const float* Ab = qrel + (size_t)b * Lq * DREL;
  const float* Kb = krel + (size_t)b * Lq * DREL;

  float acc[8][8];
#pragma unroll
  for (int i = 0; i < 8; ++i)
#pragma unroll
    for (int j = 0; j < 8; ++j) acc[i][j] = 0.f;

  for (int k0 = 0; k0 < DREL; k0 += 16) {
    {
      const float* ap = Ab + (size_t)(q0 + lr) * DREL + k0 + lk;
      float4 a0 = *(const float4*)(ap);
      float4 a1 = *(const float4*)(ap + 4);
      As[lk + 0][lr] = a0.x; As[lk + 1][lr] = a0.y;
      As[lk + 2][lr] = a0.z; As[lk + 3][lr] = a0.w;
      As[lk + 4][lr] = a1.x; As[lk + 5][lr] = a1.y;
      As[lk + 6][lr] = a1.z; As[lk + 7][lr] = a1.w;
    }
    {
      const float* bp = Kb + (size_t)(j0 + lr) * DREL + k0 + lk;
      float4 b0 = *(const float4*)(bp);
      float4 b1 = *(const float4*)(bp + 4);
      Bs[lk + 0][lr] = b0.x; Bs[lk + 1][lr] = b0.y;
      Bs[lk + 2][lr] = b0.z; Bs[lk + 3][lr] = b0.w;
      Bs[lk + 4][lr] = b1.x; Bs[lk + 5][lr] = b1.y;
      Bs[lk + 6][lr] = b1.z; Bs[lk + 7][lr] = b1.w;
    }
    __syncthreads();
#pragma unroll
    for (int kk = 0; kk < 16; ++kk) {
      float af[8], bf[8];
#pragma unroll
      for (int i = 0; i < 8; ++i) af[i] = As[kk][ty * 8 + i];
#pragma unroll
      for (int j = 0; j < 8; ++j) bf[j] = Bs[kk][tx * 8 + j];
#pragma unroll
      for (int i = 0; i < 8; ++i)
#pragma unroll
        for (int j = 0; j < 8; ++j) acc[i][j] += af[i] * bf[j];
    }
    __syncthreads();
  }

  const float sc = 0.125f;  // DREL^-0.5
#pragma unroll
  for (int i = 0; i < 8; ++i) {
    float* cp = S + ((size_t)b * Lq + q0 + ty * 8 + i) * Lq + j0 + tx * 8;
    ((float4*)cp)[0] = make_float4(acc[i][0] * sc, acc[i][1] * sc, acc[i][2] * sc, acc[i][3] * sc);
    ((float4*)cp)[1] = make_float4(acc[i][4] * sc, acc[i][5] * sc, acc[i][6] * sc, acc[i][7] * sc);
  }
}

// ---------------------------------------------------------------------------
// Wave-per-row exact top-K select + mask emission, all in registers.
// ---------------------------------------------------------------------------
__global__ __launch_bounds__(256) void relselect(const float* __restrict__ S,
                                                 uint32_t* __restrict__ mask) {
  const int w = threadIdx.x >> 6;
  const int lane = threadIdx.x & 63;
  const int ridx = blockIdx.x * 4 + w;      // = b*Lq + qi
  const int qi = ridx & (Lq - 1);
  const int n = qi + 1;
  const float* srow = S + (size_t)ridx * Lq;

  uint32_t keys[32];
#pragma unroll
  for (int t = 0; t < 32; ++t) {
    const int j = t * 64 + lane;
    const uint32_t u = __float_as_uint(srow[j]);
    const uint32_t k = (u & 0x80000000u) ? ~u : (u | 0x80000000u);
    keys[t] = (j < n) ? k : 0u;   // 0 never matches any candidate prefix
  }

  uint32_t kth = 0u;
  if (n > KTOP) {
    uint32_t pref = 0u;
    int rem = KTOP;
    for (int bit = 31; bit >= 0; --bit) {
      const uint32_t cand = pref | (1u << bit);
      const uint32_t lim = 1u << bit;
      int c = 0;
#pragma unroll
      for (int t = 0; t < 32; ++t) c += ((keys[t] ^ cand) < lim) ? 1 : 0;
      c += __shfl_xor(c, 1);
      c += __shfl_xor(c, 2);
      c += __shfl_xor(c, 4);
      c += __shfl_xor(c, 8);
      c += __shfl_xor(c, 16);
      c += __shfl_xor(c, 32);
      if (c >= rem) pref = cand;
      else rem -= c;
    }
    kth = pref;
  }

  uint32_t* mrow = mask + (size_t)ridx * (Lq / 32);
#pragma unroll
  for (int t = 0; t < 32; ++t) {
    const int j = t * 64 + lane;
    const bool ok = (j < n) && (keys[t] >= kth || j == qi);  // kth=0 -> causal-only
    const unsigned long long bal = __ballot(ok);
    if (lane == 0) {
      mrow[2 * t] = (uint32_t)bal;
      mrow[2 * t + 1] = (uint32_t)(bal >> 32);
    }
  }
}

// ---------------------------------------------------------------------------
// Flash attention v3: TK=64 tiles, double-buffered LDS with reg-staged
// async split (T14), one barrier per tile, setprio around MFMA cluster (T5).
// Q is pre-scaled by DH^-0.5*log2(e) at weight-conversion time.
// Reads fused QKV buffer with row stride 3*Dm (q at +0, k at +2048, v at +4096).
// ---------------------------------------------------------------------------
#define ATQ 128
#define TK 64
__global__ __launch_bounds__(512, 4) void attn_flash3(const unsigned short* __restrict__ qkv,
                                                      const uint32_t* __restrict__ mask,
                                                      unsigned short* __restrict__ ctx) {
  __shared__ unsigned short Ks[2][TK][136];      // 34816 B
  __shared__ unsigned short Vt[2][2][64][72];    // 36864 B  [buf][half][d>>1][(d&1)*32+slot]
  __shared__ uint32_t mw[2][ATQ][2];             //  2048 B

  // z=0: heavy-first; z=1: light-first -> co-resident pairs (id, id+256) balance
  const int qt = (blockIdx.z == 0) ? ((Lq / ATQ) - 1 - (int)blockIdx.x) : (int)blockIdx.x;
  const int h = blockIdx.y;
  const int b = blockIdx.z;
  const int tid = threadIdx.x;
  const int w = tid >> 6;          // wave 0..7
  const int lane = tid & 63;
  const int l15 = lane & 15;
  const int quad = lane >> 4;
  const int q0 = qt * ATQ;
  const int STR = 3 * Dm;

  const unsigned short* kbp = qkv + 2048;
  const unsigned short* vbp = qkv + 4096;

  // Q fragment (already scaled by DH^-0.5*log2e via Wq conversion)
  const int myq = q0 + w * 16 + l15;
  const unsigned short* qrow = qkv + (size_t)(b * Lq + myq) * STR + h * DH;
  bf16x8 bq[4];
#pragma unroll
  for (int kk = 0; kk < 4; ++kk) bq[kk] = *(const bf16x8*)(qrow + kk * 32 + quad * 8);

  f32x4 O[8];  // O^T: O[f][r] = ctx[q=l15][f*16 + quad*4 + r]
#pragma unroll
  for (int f = 0; f < 8; ++f) O[f] = (f32x4){0.f, 0.f, 0.f, 0.f};
  float l_lane = 0.f;

  const int nt = (q0 + ATQ) / TK;   // = 2*qt + 2

  // staging geometry: waves 0-3 stage K + mask, waves 4-7 stage V
  const int skey = (tid & 255) >> 2;     // K: key 0..63
  const int scg  = tid & 3;              // K: dim group of 32
  const int mq   = (tid & 255) >> 1;     // mask: q row 0..127
  const int msel = tid & 1;
  const int tv = tid - 256;
  const int vkp = tv & 31;               // V: key pair 0..31
  const int vdg = (tv >> 5) & 7;         // V: dim group of 16
  const int vhalf = vkp >> 4;
  const int vkp16 = vkp & 15;
  const int dwc = ((vkp16 >> 1) & 3) * 4 + (vkp16 >> 3) * 2 + (vkp16 & 1);

  const uint32_t* mrow_base = mask + (size_t)(b * Lq + q0 + mq) * (Lq / 32) + msel;
  const unsigned short* krow_base = kbp + (size_t)(b * Lq + skey) * STR + h * DH + scg * 32;
  const unsigned short* vrow_base = vbp + (size_t)(b * Lq + 2 * vkp) * STR + h * DH + vdg * 16;

  bf16x8 r0, r1, r2, r3;
  uint32_t mreg = 0;

#define LOADREGS(KT)                                                       \
  do {                                                                     \
    const int kbase_ = (KT) * TK;                                          \
    if (tid < 256) {                                                       \
      const unsigned short* kr = krow_base + (size_t)kbase_ * STR;         \
      r0 = *(const bf16x8*)(kr);                                           \
      r1 = *(const bf16x8*)(kr + 8);                                       \
      r2 = *(const bf16x8*)(kr + 16);                                      \
      r3 = *(const bf16x8*)(kr + 24);                                      \
      mreg = mrow_base[(KT) * 2];                                          \
    } else {                                                               \
      const unsigned short* vr = vrow_base + (size_t)kbase_ * STR;         \
      r0 = *(const bf16x8*)(vr);                                           \
      r1 = *(const bf16x8*)(vr + 8);                                       \
      r2 = *(const bf16x8*)(vr + STR);                                     \
      r3 = *(const bf16x8*)(vr + STR + 8);                                 \
    }                                                                      \
  } while (0)

#define WRITELDS(BUF)                                                      \
  do {                                                                     \
    if (tid < 256) {                                                       \
      *(bf16x8*)&Ks[BUF][skey][scg * 32 + 0]  = r0;                        \
      *(bf16x8*)&Ks[BUF][skey][scg * 32 + 8]  = r1;                        \
      *(bf16x8*)&Ks[BUF][skey][scg * 32 + 16] = r2;                        \
      *(bf16x8*)&Ks[BUF][skey][scg * 32 + 24] = r3;                        \
      mw[BUF][mq][msel] = mreg;                                            \
    } else {                                                               \
      _Pragma("unroll") for (int i = 0; i < 8; ++i) {                      \
        const int d = vdg * 16 + i;                                        \
        const uint32_t pk = (uint32_t)(unsigned short)r0[i] |              \
                            ((uint32_t)(unsigned short)r2[i] << 16);       \
        ((uint32_t*)&Vt[BUF][vhalf][d >> 1][0])[(d & 1) * 16 + dwc] = pk;  \
      }                                                                    \
      _Pragma("unroll") for (int i = 0; i < 8; ++i) {                      \
        const int d = vdg * 16 + 8 + i;                                    \
        const uint32_t pk = (uint32_t)(unsigned short)r1[i] |              \
                            ((uint32_t)(unsigned short)r3[i] << 16);       \
        ((uint32_t*)&Vt[BUF][vhalf][d >> 1][0])[(d & 1) * 16 + dwc] = pk;  \
      }                                                                    \
    }                                                                      \
  } while (0)

  // prologue: tile 0 into buffer 0
  LOADREGS(0);
  WRITELDS(0);
  __syncthreads();

  int buf = 0;
  for (int kt = 0; kt < nt; ++kt) {
    const bool more = (kt + 1 < nt);
    if (more) LOADREGS(kt + 1);   // issue global loads; consumed after compute

    __builtin_amdgcn_s_setprio(1);
#pragma unroll
    for (int hh = 0; hh < 2; ++hh) {
      // S^T = K Q^T for 32-key half hh
      f32x4 acc0 = (f32x4){0.f, 0.f, 0.f, 0.f};
      f32x4 acc1 = acc0;
#pragma unroll
      for (int kk = 0; kk < 4; ++kk) {
        bf16x8 a0 = *(const bf16x8*)&Ks[buf][hh * 32 + l15][kk * 32 + quad * 8];
        bf16x8 a1 = *(const bf16x8*)&Ks[buf][hh * 32 + 16 + l15][kk * 32 + quad * 8];
        acc0 = __builtin_amdgcn_mfma_f32_16x16x32_bf16(a0, bq[kk], acc0, 0, 0, 0);
        acc1 = __builtin_amdgcn_mfma_f32_16x16x32_bf16(a1, bq[kk], acc1, 0, 0, 0);
      }

      const uint32_t mword = mw[buf][w * 16 + l15][hh];
      bf16x8 bp;
      float ps = 0.f;
#pragma unroll
      for (int r = 0; r < 4; ++r) {
        const float p0 = ((mword >> (quad * 4 + r)) & 1u) ? __builtin_amdgcn_exp2f(acc0[r]) : 0.f;
        const float p1 = ((mword >> (16 + quad * 4 + r)) & 1u) ? __builtin_amdgcn_exp2f(acc1[r]) : 0.f;
        ps += p0 + p1;
        bp[r] = (short)f2bf(p0);
        bp[4 + r] = (short)f2bf(p1);
      }
      l_lane += ps;

      // O^T += V^T P^T
#pragma unroll
      for (int f = 0; f < 8; ++f) {
        const int d = f * 16 + l15;
        bf16x8 av = *(const bf16x8*)&Vt[buf][hh][d >> 1][(d & 1) * 32 + quad * 8];
        O[f] = __builtin_amdgcn_mfma_f32_16x16x32_bf16(av, bp, O[f], 0, 0, 0);
      }
    }
    __builtin_amdgcn_s_setprio(0);

    if (more) WRITELDS(buf ^ 1);   // other buffer: safe vs concurrent compute(buf)
    __syncthreads();
    buf ^= 1;
  }
#undef LOADREGS
#undef WRITELDS

  l_lane += __shfl_xor(l_lane, 16);
  l_lane += __shfl_xor(l_lane, 32);
  const float rl = 1.0f / l_lane;

  unsigned short* orow = ctx + ((size_t)(b * Lq + q0 + w * 16 + l15)) * Dm + h * DH;
#pragma unroll
  for (int f = 0; f < 8; ++f) {
    ushort4 o4;
    o4.x = f2bf(O[f][0] * rl);
    o4.y = f2bf(O[f][1] * rl);
    o4.z = f2bf(O[f][2] * rl);
    o4.w = f2bf(O[f][3] * rl);
    *(ushort4*)(orow + f * 16 + quad * 4) = o4;
  }
}

// ---------------------------------------------------------------------------
extern "C" void kernel_launch(void* const* d_in, const int* in_sizes, int n_in,
                              void* d_out, int out_size, void* d_ws, size_t ws_size,
                              hipStream_t stream) {
  const float* hs  = (const float*)d_in[0];
  const float* rel = (const float*)d_in[1];
  const float* Wqr = (const float*)d_in[2];
  const float* Wkr = (const float*)d_in[3];
  const float* Wq  = (const float*)d_in[4];
  const float* Wk  = (const float*)d_in[5];
  const float* Wv  = (const float*)d_in[6];
  const float* Wo  = (const float*)d_in[7];
  float* out = (float*)d_out;

  const int M = Bb * Lq;   // 4096
  const int ND = Dm * Dm;
  char* ws = (char*)d_ws;
  size_t off = 0;
  float* qrel = (float*)(ws + off); off += (size_t)M * DREL * 4;
  float* krel = (float*)(ws + off); off += (size_t)M * DREL * 4;
  uint32_t* maskb = (uint32_t*)(ws + off); off += (size_t)M * (Lq / 32) * 4;
  float* partq = (float*)(ws + off); off += (size_t)RKS * M * DREL * 4;
  float* partk = (float*)(ws + off); off += (size_t)RKS * M * DREL * 4;
  // bf16 staging region; Sbuf (B*L*L fp32 = 33.5 MB) is ALIASED onto its head:
  // Sbuf is consumed by relselect before any bf16 buffer is written (in-order stream).
  float* Sbuf = (float*)(ws + off);
  unsigned short* hsb  = (unsigned short*)(ws + off); off += (size_t)M * Dm * 2;
  unsigned short* qkvb = (unsigned short*)(ws + off); off += (size_t)M * 3 * Dm * 2;
  unsigned short* ctxb = (unsigned short*)(ws + off); off += (size_t)M * Dm * 2;
  unsigned short* Wqb  = (unsigned short*)(ws + off); off += (size_t)ND * 2;  // must stay
  unsigned short* Wkb  = (unsigned short*)(ws + off); off += (size_t)ND * 2;  // contiguous
  unsigned short* Wvb  = (unsigned short*)(ws + off); off += (size_t)ND * 2;  // (fused QKV W)
  unsigned short* Wob  = (unsigned short*)(ws + off); off += (size_t)ND * 2;

  const dim3 blk(256);
  const int hsN8 = M * Dm / 8;
  const int wN8  = ND / 8;
  const float QSCALE = 0.08838834764831845f * 1.4426950408889634f;  // DH^-0.5 * log2(e)

  // rel pipeline: fp32-exact projections -> dense triangular scores -> wave select
  relproj<<<dim3(RKS, M / 128), blk, 0, stream>>>(rel, Wqr, partq, M);
  relproj<<<dim3(RKS, M / 128), blk, 0, stream>>>(rel, Wkr, partk, M);
  relreduce<<<(M * DREL / 4 + 255) / 256, blk, 0, stream>>>(partq, partk, qrel, krel, M * DREL / 4);
  relscore<<<dim3(Lq / 128, Lq / 128, Bb), blk, 0, stream>>>(qrel, krel, Sbuf);
  relselect<<<M / 4, blk, 0, stream>>>(Sbuf, maskb);

  // bf16 conversions (overwrite Sbuf region only after relselect has consumed it)
  conv_bf16<<<(hsN8 + 255) / 256, blk, 0, stream>>>(hs, hsb, hsN8, 1.0f);
  conv_bf16<<<(wN8 + 255) / 256, blk, 0, stream>>>(Wq, Wqb, wN8, QSCALE);
  conv_bf16<<<(wN8 + 255) / 256, blk, 0, stream>>>(Wk, Wkb, wN8, 1.0f);
  conv_bf16<<<(wN8 + 255) / 256, blk, 0, stream>>>(Wv, Wvb, wN8, 1.0f);
  conv_bf16<<<(wN8 + 255) / 256, blk, 0, stream>>>(Wo, Wob, wN8, 1.0f);

  // fused QKV projection (bf16 MFMA): C[M, 3*Dm] = hsb @ [Wq;Wk;Wv]^T
  gemm_bf<true><<<dim3(3 * Dm / 128, M / 128), blk, 0, stream>>>(hsb, Wqb, qkvb, M, 3 * Dm, Dm);

  // flash attention v3
  attn_flash3<<<dim3(Lq / ATQ, Hh, Bb), dim3(512), 0, stream>>>(qkvb, maskb, ctxb);

  // O projection -> fp32 out
  gemm_bf<false><<<dim3(Dm / 128, M / 128), blk, 0, stream>>>(ctxb, Wob, out, M, Dm, Dm);
}

// Round 2
// 489.826 us; speedup vs baseline: 1.2206x; 1.0699x over previous
//
#include <hip/hip_runtime.h>
#include <math.h>
#include <stdint.h>

// Problem constants (match reference)
#define Bb 2
#define Lq 2048
#define Dm 2048
#define Hh 16
#define DH 128
#define DREL 64
#define KTOP 512   // 0.25 * L

#define NEG_INF (-__builtin_huge_valf())

typedef __attribute__((ext_vector_type(8))) short bf16x8;   // 8 bf16 (4 VGPRs)
typedef __attribute__((ext_vector_type(4))) float f32x4;

static __device__ __forceinline__ unsigned short f2bf(float f) {
  unsigned int u = __float_as_uint(f);
  u += 0x7fffu + ((u >> 16) & 1u);   // RNE
  return (unsigned short)(u >> 16);
}

// async global->LDS, 16B per lane; LDS dest = wave-uniform base + lane*16
static __device__ __forceinline__ void gload16(const void* g, void* lds) {
  __builtin_amdgcn_global_load_lds(
      (const __attribute__((address_space(1))) uint32_t*)(uintptr_t)g,
      (__attribute__((address_space(3))) uint32_t*)(uint32_t)(uintptr_t)lds,
      16, 0, 0);
}

// ---------------------------------------------------------------------------
// fp32 -> bf16 elementwise with optional scale (n8 = n/8)
// ---------------------------------------------------------------------------
__global__ __launch_bounds__(256) void conv_bf16(const float* __restrict__ in,
                                                 unsigned short* __restrict__ out,
                                                 int n8, float scale) {
  const int i = blockIdx.x * 256 + threadIdx.x;
  if (i >= n8) return;
  const float4 f0 = ((const float4*)in)[2 * i];
  const float4 f1 = ((const float4*)in)[2 * i + 1];
  bf16x8 o;
  o[0] = (short)f2bf(f0.x * scale); o[1] = (short)f2bf(f0.y * scale);
  o[2] = (short)f2bf(f0.z * scale); o[3] = (short)f2bf(f0.w * scale);
  o[4] = (short)f2bf(f1.x * scale); o[5] = (short)f2bf(f1.y * scale);
  o[6] = (short)f2bf(f1.z * scale); o[7] = (short)f2bf(f1.w * scale);
  *(bf16x8*)(out + 8 * (size_t)i) = o;
}

// 4 weight matrices -> bf16, one launch (blockIdx.y selects); w0 gets scale s0.
__global__ __launch_bounds__(256) void conv_bf16_w4(const float* __restrict__ w0,
                                                    const float* __restrict__ w1,
                                                    const float* __restrict__ w2,
                                                    const float* __restrict__ w3,
                                                    unsigned short* __restrict__ out,
                                                    float s0) {
  const int sel = blockIdx.y;
  const float* in = (sel == 0) ? w0 : (sel == 1) ? w1 : (sel == 2) ? w2 : w3;
  const float scale = (sel == 0) ? s0 : 1.0f;
  const int i = blockIdx.x * 256 + threadIdx.x;   // grid.x = ND/8/256 exact
  const float4 f0 = ((const float4*)in)[2 * i];
  const float4 f1 = ((const float4*)in)[2 * i + 1];
  bf16x8 o;
  o[0] = (short)f2bf(f0.x * scale); o[1] = (short)f2bf(f0.y * scale);
  o[2] = (short)f2bf(f0.z * scale); o[3] = (short)f2bf(f0.w * scale);
  o[4] = (short)f2bf(f1.x * scale); o[5] = (short)f2bf(f1.y * scale);
  o[6] = (short)f2bf(f1.z * scale); o[7] = (short)f2bf(f1.w * scale);
  *(bf16x8*)(out + (size_t)sel * Dm * Dm + 8 * (size_t)i) = o;
}

// ---------------------------------------------------------------------------
// 256x256 8-wave deep-pipelined bf16 GEMM (T1+T2+T3/T4+T5).
// C[M,N] = A[M,K] @ W[N,K]^T, fp32 accum. M%256==0, N%256==0, K%64==0.
// LDS: 2 dbuf x {A,B} x 2 halves x [128][64] bf16 = 128 KiB, XOR-swizzled.
// Per K-tile: 4 phases (C-quadrants of 16 MFMA) + raw s_barrier between;
// all 8 global_load_lds for tile t+1 issued at phase 0; single vmcnt drain
// at the boundary __syncthreads().
// ---------------------------------------------------------------------------
template <bool BF16OUT>
__global__ __launch_bounds__(512, 2) void gemm256(const unsigned short* __restrict__ A,
                                                  const unsigned short* __restrict__ W,
                                                  void* __restrict__ Cv,
                                                  int M, int N, int Kd) {
  __shared__ unsigned short As[2][2][128][64];   // [buf][half][row][col^swz]
  __shared__ unsigned short Bs[2][2][128][64];

  const int tid = threadIdx.x;
  const int w = tid >> 6;
  const int lane = tid & 63;
  const int l15 = lane & 15;
  const int quad = lane >> 4;
  const int wm = w >> 2;        // 0..1 -> row half
  const int wn = w & 3;         // 0..3 -> 64-col slice

  // T1: bijective XCD swizzle on flattened grid (nwg % 8 == 0 for our shapes)
  const int gx = N >> 8;
  const int nwg = (M >> 8) * gx;
  const int cpx = nwg >> 3;
  const int bid = (int)blockIdx.x;
  const int lin = (bid & 7) * cpx + (bid >> 3);
  const int bx = lin % gx, by = lin / gx;
  const int m0 = by * 256, n0 = bx * 256;

  // staging geometry: one gload16 call-site = 64 rows (8 waves x 8 rows),
  // lane -> row (lane>>3), 16B slot (lane&7). Inverse swizzle on the GLOBAL
  // source slot so that swizzled ds_reads see logical data (rule 21).
  const int srow = lane >> 3;
  const int sslot = (lane & 7) ^ srow;
  const size_t rowK = (size_t)Kd;
  const unsigned short* aG0 = A + (size_t)(m0 + w * 8 + srow) * rowK + sslot * 8;
  const unsigned short* aG1 = aG0 + 64 * rowK;
  const unsigned short* aG2 = aG0 + 128 * rowK;
  const unsigned short* aG3 = aG0 + 192 * rowK;
  const unsigned short* bG0 = W + (size_t)(n0 + w * 8 + srow) * rowK + sslot * 8;
  const unsigned short* bG1 = bG0 + 64 * rowK;
  const unsigned short* bG2 = bG0 + 128 * rowK;
  const unsigned short* bG3 = bG0 + 192 * rowK;

  f32x4 acc[8][4];
#pragma unroll
  for (int i = 0; i < 8; ++i)
#pragma unroll
    for (int j = 0; j < 4; ++j) acc[i][j] = (f32x4){0.f, 0.f, 0.f, 0.f};

  bf16x8 af[4][2];   // 4 m-frags x 2 k-slices (reused across m-halves)
  bf16x8 bfr[2][2];  // 2 n-frags x 2 k-slices (reused across n-halves)
  const int swz = (l15 & 7) * 8;   // element-granularity XOR (8-slot spread)

#define STAGE(BUF, T)                                         \
  do {                                                        \
    const size_t ko = (size_t)(T) * 64;                       \
    gload16(aG0 + ko, &As[BUF][0][w * 8][0]);                 \
    gload16(aG1 + ko, &As[BUF][0][64 + w * 8][0]);            \
    gload16(aG2 + ko, &As[BUF][1][w * 8][0]);                 \
    gload16(aG3 + ko, &As[BUF][1][64 + w * 8][0]);            \
    gload16(bG0 + ko, &Bs[BUF][0][w * 8][0]);                 \
    gload16(bG1 + ko, &Bs[BUF][0][64 + w * 8][0]);            \
    gload16(bG2 + ko, &Bs[BUF][1][w * 8][0]);                 \
    gload16(bG3 + ko, &Bs[BUF][1][64 + w * 8][0]);            \
  } while (0)

#define LOAD_A(BUF, MH)                                                        \
  _Pragma("unroll") for (int mi = 0; mi < 4; ++mi)                             \
    _Pragma("unroll") for (int ks = 0; ks < 2; ++ks)                           \
      af[mi][ks] = *(const bf16x8*)&As[BUF][wm][(MH) * 64 + mi * 16 + l15]     \
                                      [(ks * 32 + quad * 8) ^ swz];

#define LOAD_B(BUF, NH)                                                        \
  _Pragma("unroll") for (int ni = 0; ni < 2; ++ni)                             \
    _Pragma("unroll") for (int ks = 0; ks < 2; ++ks)                           \
      bfr[ni][ks] = *(const bf16x8*)&Bs[BUF][wn >> 1]                          \
          [(wn & 1) * 64 + ((NH) * 2 + ni) * 16 + l15]                         \
          [(ks * 32 + quad * 8) ^ swz];

#define PHASE_MFMA(MH, NH)                                                     \
  do {                                                                         \
    __builtin_amdgcn_s_setprio(1);                                             \
    _Pragma("unroll") for (int mi = 0; mi < 4; ++mi)                           \
      _Pragma("unroll") for (int ni = 0; ni < 2; ++ni) {                       \
        acc[(MH) * 4 + mi][(NH) * 2 + ni] =                                    \
            __builtin_amdgcn_mfma_f32_16x16x32_bf16(                           \
                af[mi][0], bfr[ni][0], acc[(MH) * 4 + mi][(NH) * 2 + ni], 0, 0, 0); \
        acc[(MH) * 4 + mi][(NH) * 2 + ni] =                                    \
            __builtin_amdgcn_mfma_f32_16x16x32_bf16(                           \
                af[mi][1], bfr[ni][1], acc[(MH) * 4 + mi][(NH) * 2 + ni], 0, 0, 0); \
      }                                                                        \
    __builtin_amdgcn_s_setprio(0);                                             \
  } while (0)

  // prologue: tile 0 -> buf 0
  STAGE(0, 0);
  __syncthreads();

  const int nt = Kd >> 6;
  int buf = 0;
  for (int t = 0; t < nt; ++t) {
    if (t + 1 < nt) STAGE(buf ^ 1, t + 1);   // issue early; drained at boundary

    // phase 0: quadrant (m-half 0, n-half 0)
    LOAD_A(buf, 0);
    LOAD_B(buf, 0);
    PHASE_MFMA(0, 0);
    __builtin_amdgcn_s_barrier();

    // phase 1: (0, 1)
    LOAD_B(buf, 1);
    PHASE_MFMA(0, 1);
    __builtin_amdgcn_s_barrier();

    // phase 2: (1, 1)
    LOAD_A(buf, 1);
    PHASE_MFMA(1, 1);
    __builtin_amdgcn_s_barrier();

    // phase 3: (1, 0)
    LOAD_B(buf, 0);
    PHASE_MFMA(1, 0);

    __syncthreads();   // boundary: drains vmcnt(0) -> tile t+1 landed
    buf ^= 1;
  }
#undef STAGE
#undef LOAD_A
#undef LOAD_B
#undef PHASE_MFMA

#pragma unroll
  for (int im = 0; im < 8; ++im) {
#pragma unroll
    for (int in = 0; in < 4; ++in) {
      const int col = n0 + wn * 64 + in * 16 + l15;
#pragma unroll
      for (int r = 0; r < 4; ++r) {
        const int row = m0 + wm * 128 + im * 16 + quad * 4 + r;
        if (BF16OUT)
          ((unsigned short*)Cv)[(size_t)row * N + col] = f2bf(acc[im][in][r]);
        else
          ((float*)Cv)[(size_t)row * N + col] = acc[im][in][r];
      }
    }
  }
}

// ---------------------------------------------------------------------------
// Split-K fp32 rel projection, q and k fused via blockIdx.z.
// ---------------------------------------------------------------------------
#define RKS 8
__global__ __launch_bounds__(256) void relproj2(const float* __restrict__ A,
                                                const float* __restrict__ Wqr,
                                                const float* __restrict__ Wkr,
                                                float* __restrict__ partq,
                                                float* __restrict__ partk, int M) {
  const float* W = blockIdx.z ? Wkr : Wqr;
  float* part = blockIdx.z ? partk : partq;
  __shared__ float As[16][128];
  __shared__ float Bs[16][64];
  const int ks = blockIdx.x;
  const int m0 = blockIdx.y * 128;
  const int tid = threadIdx.x;
  const int tx = tid & 15;
  const int ty = tid >> 4;
  const int lr = tid >> 1, lk = (tid & 1) * 8;
  const int wr = tid >> 2, wk = (tid & 3) * 4;

  float acc[8][4];
#pragma unroll
  for (int i = 0; i < 8; ++i)
#pragma unroll
    for (int j = 0; j < 4; ++j) acc[i][j] = 0.f;

  const int k00 = ks * (Dm / RKS);
  for (int k0 = k00; k0 < k00 + Dm / RKS; k0 += 16) {
    {
      const float* ap = A + (size_t)(m0 + lr) * Dm + k0 + lk;
      float4 a0 = *(const float4*)(ap);
      float4 a1 = *(const float4*)(ap + 4);
      As[lk + 0][lr] = a0.x; As[lk + 1][lr] = a0.y;
      As[lk + 2][lr] = a0.z; As[lk + 3][lr] = a0.w;
      As[lk + 4][lr] = a1.x; As[lk + 5][lr] = a1.y;
      As[lk + 6][lr] = a1.z; As[lk + 7][lr] = a1.w;
    }
    {
      const float* bp = W + (size_t)wr * Dm + k0 + wk;
      float4 b0 = *(const float4*)(bp);
      Bs[wk + 0][wr] = b0.x; Bs[wk + 1][wr] = b0.y;
      Bs[wk + 2][wr] = b0.z; Bs[wk + 3][wr] = b0.w;
    }
    __syncthreads();
#pragma unroll
    for (int kk = 0; kk < 16; ++kk) {
      float af[8], bf[4];
#pragma unroll
      for (int i = 0; i < 8; ++i) af[i] = As[kk][ty * 8 + i];
#pragma unroll
      for (int j = 0; j < 4; ++j) bf[j] = Bs[kk][tx * 4 + j];
#pragma unroll
      for (int i = 0; i < 8; ++i)
#pragma unroll
        for (int j = 0; j < 4; ++j) acc[i][j] += af[i] * bf[j];
    }
    __syncthreads();
  }

#pragma unroll
  for (int i = 0; i < 8; ++i) {
    float* pp = part + ((size_t)ks * M + m0 + ty * 8 + i) * DREL + tx * 4;
    *(float4*)pp = make_float4(acc[i][0], acc[i][1], acc[i][2], acc[i][3]);
  }
}

__global__ __launch_bounds__(256) void relreduce(const float* __restrict__ pq,
                                                 const float* __restrict__ pk,
                                                 float* __restrict__ qrel,
                                                 float* __restrict__ krel, int n4) {
  const int i = blockIdx.x * 256 + threadIdx.x;
  if (i >= n4) return;
  float4 sq = make_float4(0, 0, 0, 0), sk = sq;
  for (int s = 0; s < RKS; ++s) {
    float4 a = ((const float4*)pq)[(size_t)s * n4 + i];
    float4 b = ((const float4*)pk)[(size_t)s * n4 + i];
    sq.x += a.x; sq.y += a.y; sq.z += a.z; sq.w += a.w;
    sk.x += b.x; sk.y += b.y; sk.z += b.z; sk.w += b.w;
  }
  ((float4*)qrel)[i] = sq;
  ((float4*)krel)[i] = sk;
}

// ---------------------------------------------------------------------------
// Dense triangular rel-score GEMM: S[b][q][j] = (qrel[b,q,:]·krel[b,j,:])*DREL^-0.5
// ---------------------------------------------------------------------------
__global__ __launch_bounds__(256) void relscore(const float* __restrict__ qrel,
                                                const float* __restrict__ krel,
                                                float* __restrict__ S) {
  const int jt = blockIdx.x, qt = blockIdx.y, b = blockIdx.z;
  if (jt > qt) return;
  __shared__ float As[16][128];
  __shared__ float Bs[16][128];
  const int tid = threadIdx.x;
  const int q0 = qt * 128, j0 = jt * 128;
  const int tx = tid & 15, ty = tid >> 4;
  const int lr = tid >> 1, lk = (tid & 1) * 8;
  const float* Ab = qrel + (size_t)b * Lq * DREL;
  const float* Kb = krel + (size_t)b * Lq * DREL;

  float acc[8][8];
#pragma unroll
  for (int i = 0; i < 8; ++i)
#pragma unroll
    for (int j = 0; j < 8; ++j) acc[i][j] = 0.f;

  for (int k0 = 0; k0 < DREL; k0 += 16) {
    {
      const float* ap = Ab + (size_t)(q0 + lr) * DREL + k0 + lk;
      float4 a0 = *(const float4*)(ap);
      float4 a1 = *(const float4*)(ap + 4);
      As[lk + 0][lr] = a0.x; As[lk + 1][lr] = a0.y;
      As[lk + 2][lr] = a0.z; As[lk + 3][lr] = a0.w;
      As[lk + 4][lr] = a1.x; As[lk + 5][lr] = a1.y;
      As[lk + 6][lr] = a1.z; As[lk + 7][lr] = a1.w;
    }
    {
      const float* bp = Kb + (size_t)(j0 + lr) * DREL + k0 + lk;
      float4 b0 = *(const float4*)(bp);
      float4 b1 = *(const float4*)(bp + 4);
      Bs[lk + 0][lr] = b0.x; Bs[lk + 1][lr] = b0.y;
      Bs[lk + 2][lr] = b0.z; Bs[lk + 3][lr] = b0.w;
      Bs[lk + 4][lr] = b1.x; Bs[lk + 5][lr] = b1.y;
      Bs[lk + 6][lr] = b1.z; Bs[lk + 7][lr] = b1.w;
    }
    __syncthreads();
#pragma unroll
    for (int kk = 0; kk < 16; ++kk) {
      float af[8], bf[8];
#pragma unroll
      for (int i = 0; i < 8; ++i) af[i] = As[kk][ty * 8 + i];
#pragma unroll
      for (int j = 0; j < 8; ++j) bf[j] = Bs[kk][tx * 8 + j];
#pragma unroll
      for (int i = 0; i < 8; ++i)
#pragma unroll
        for (int j = 0; j < 8; ++j) acc[i][j] += af[i] * bf[j];
    }
    __syncthreads();
  }

  const float sc = 0.125f;  // DREL^-0.5
#pragma unroll
  for (int i = 0; i < 8; ++i) {
    float* cp = S + ((size_t)b * Lq + q0 + ty * 8 + i) * Lq + j0 + tx * 8;
    ((float4*)cp)[0] = make_float4(acc[i][0] * sc, acc[i][1] * sc, acc[i][2] * sc, acc[i][3] * sc);
    ((float4*)cp)[1] = make_float4(acc[i][4] * sc, acc[i][5] * sc, acc[i][6] * sc, acc[i][7] * sc);
  }
}

// ---------------------------------------------------------------------------
// Wave-per-row exact top-K select + mask emission, all in registers.
// ---------------------------------------------------------------------------
__global__ __launch_bounds__(256) void relselect(const float* __restrict__ S,
                                                 uint32_t* __restrict__ mask) {
  const int w = threadIdx.x >> 6;
  const int lane = threadIdx.x & 63;
  const int ridx = blockIdx.x * 4 + w;      // = b*Lq + qi
  const int qi = ridx & (Lq - 1);
  const int n = qi + 1;
  const float* srow = S + (size_t)ridx * Lq;

  uint32_t keys[32];
#pragma unroll
  for (int t = 0; t < 32; ++t) {
    const int j = t * 64 + lane;
    const uint32_t u = __float_as_uint(srow[j]);
    const uint32_t k = (u & 0x80000000u) ? ~u : (u | 0x80000000u);
    keys[t] = (j < n) ? k : 0u;   // 0 never matches any candidate prefix
  }

  uint32_t kth = 0u;
  if (n > KTOP) {
    uint32_t pref = 0u;
    int rem = KTOP;
    for (int bit = 31; bit >= 0; --bit) {
      const uint32_t cand = pref | (1u << bit);
      const uint32_t lim = 1u << bit;
      int c = 0;
#pragma unroll
      for (int t = 0; t < 32; ++t) c += ((keys[t] ^ cand) < lim) ? 1 : 0;
      c += __shfl_xor(c, 1);
      c += __shfl_xor(c, 2);
      c += __shfl_xor(c, 4);
      c += __shfl_xor(c, 8);
      c += __shfl_xor(c, 16);
      c += __shfl_xor(c, 32);
      if (c >= rem) pref = cand;
      else rem -= c;
    }
    kth = pref;
  }

  uint32_t* mrow = mask + (size_t)ridx * (Lq / 32);
#pragma unroll
  for (int t = 0; t < 32; ++t) {
    const int j = t * 64 + lane;
    const bool ok = (j < n) && (keys[t] >= kth || j == qi);  // kth=0 -> causal-only
    const unsigned long long bal = __ballot(ok);
    if (lane == 0) {
      mrow[2 * t] = (uint32_t)bal;
      mrow[2 * t + 1] = (uint32_t)(bal >> 32);
    }
  }
}

// ---------------------------------------------------------------------------
// Flash attention v3: TK=64 tiles, double-buffered LDS with reg-staged
// async split (T14), one barrier per tile, setprio around MFMA cluster (T5).
// Q is pre-scaled by DH^-0.5*log2(e) at weight-conversion time.
// Reads fused QKV buffer with row stride 3*Dm (q at +0, k at +2048, v at +4096).
// ---------------------------------------------------------------------------
#define ATQ 128
#define TK 64
__global__ __launch_bounds__(512, 4) void attn_flash3(const unsigned short* __restrict__ qkv,
                                                      const uint32_t* __restrict__ mask,
                                                      unsigned short* __restrict__ ctx) {
  __shared__ unsigned short Ks[2][TK][136];      // 34816 B
  __shared__ unsigned short Vt[2][2][64][72];    // 36864 B  [buf][half][d>>1][(d&1)*32+slot]
  __shared__ uint32_t mw[2][ATQ][2];             //  2048 B

  // z=0: heavy-first; z=1: light-first -> co-resident pairs (id, id+256) balance
  const int qt = (blockIdx.z == 0) ? ((Lq / ATQ) - 1 - (int)blockIdx.x) : (int)blockIdx.x;
  const int h = blockIdx.y;
  const int b = blockIdx.z;
  const int tid = threadIdx.x;
  const int w = tid >> 6;          // wave 0..7
  const int lane = tid & 63;
  const int l15 = lane & 15;
  const int quad = lane >> 4;
  const int q0 = qt * ATQ;
  const int STR = 3 * Dm;

  const unsigned short* kbp = qkv + 2048;
  const unsigned short* vbp = qkv + 4096;

  // Q fragment (already scaled by DH^-0.5*log2e via Wq conversion)
  const int myq = q0 + w * 16 + l15;
  const unsigned short* qrow = qkv + (size_t)(b * Lq + myq) * STR + h * DH;
  bf16x8 bq[4];
#pragma unroll
  for (int kk = 0; kk < 4; ++kk) bq[kk] = *(const bf16x8*)(qrow + kk * 32 + quad * 8);

  f32x4 O[8];  // O^T: O[f][r] = ctx[q=l15][f*16 + quad*4 + r]
#pragma unroll
  for (int f = 0; f < 8; ++f) O[f] = (f32x4){0.f, 0.f, 0.f, 0.f};
  float l_lane = 0.f;

  const int nt = (q0 + ATQ) / TK;   // = 2*qt + 2

  // staging geometry: waves 0-3 stage K + mask, waves 4-7 stage V
  const int skey = (tid & 255) >> 2;     // K: key 0..63
  const int scg  = tid & 3;              // K: dim group of 32
  const int mq   = (tid & 255) >> 1;     // mask: q row 0..127
  const int msel = tid & 1;
  const int tv = tid - 256;
  const int vkp = tv & 31;               // V: key pair 0..31
  const int vdg = (tv >> 5) & 7;         // V: dim group of 16
  const int vhalf = vkp >> 4;
  const int vkp16 = vkp & 15;
  const int dwc = ((vkp16 >> 1) & 3) * 4 + (vkp16 >> 3) * 2 + (vkp16 & 1);

  const uint32_t* mrow_base = mask + (size_t)(b * Lq + q0 + mq) * (Lq / 32) + msel;
  const unsigned short* krow_base = kbp + (size_t)(b * Lq + skey) * STR + h * DH + scg * 32;
  const unsigned short* vrow_base = vbp + (size_t)(b * Lq + 2 * vkp) * STR + h * DH + vdg * 16;

  bf16x8 r0, r1, r2, r3;
  uint32_t mreg = 0;

#define LOADREGS(KT)                                                       \
  do {                                                                     \
    const int kbase_ = (KT) * TK;                                          \
    if (tid < 256) {                                                       \
      const unsigned short* kr = krow_base + (size_t)kbase_ * STR;         \
      r0 = *(const bf16x8*)(kr);                                           \
      r1 = *(const bf16x8*)(kr + 8);                                       \
      r2 = *(const bf16x8*)(kr + 16);                                      \
      r3 = *(const bf16x8*)(kr + 24);                                      \
      mreg = mrow_base[(KT) * 2];                                          \
    } else {                                                               \
      const unsigned short* vr = vrow_base + (size_t)kbase_ * STR;         \
      r0 = *(const bf16x8*)(vr);                                           \
      r1 = *(const bf16x8*)(vr + 8);                                       \
      r2 = *(const bf16x8*)(vr + STR);                                     \
      r3 = *(const bf16x8*)(vr + STR + 8);                                 \
    }                                                                      \
  } while (0)

#define WRITELDS(BUF)                                                      \
  do {                                                                     \
    if (tid < 256) {                                                       \
      *(bf16x8*)&Ks[BUF][skey][scg * 32 + 0]  = r0;                        \
      *(bf16x8*)&Ks[BUF][skey][scg * 32 + 8]  = r1;                        \
      *(bf16x8*)&Ks[BUF][skey][scg * 32 + 16] = r2;                        \
      *(bf16x8*)&Ks[BUF][skey][scg * 32 + 24] = r3;                        \
      mw[BUF][mq][msel] = mreg;                                            \
    } else {                                                               \
      _Pragma("unroll") for (int i = 0; i < 8; ++i) {                      \
        const int d = vdg * 16 + i;                                        \
        const uint32_t pk = (uint32_t)(unsigned short)r0[i] |              \
                            ((uint32_t)(unsigned short)r2[i] << 16);       \
        ((uint32_t*)&Vt[BUF][vhalf][d >> 1][0])[(d & 1) * 16 + dwc] = pk;  \
      }                                                                    \
      _Pragma("unroll") for (int i = 0; i < 8; ++i) {                      \
        const int d = vdg * 16 + 8 + i;                                    \
        const uint32_t pk = (uint32_t)(unsigned short)r1[i] |              \
                            ((uint32_t)(unsigned short)r3[i] << 16);       \
        ((uint32_t*)&Vt[BUF][vhalf][d >> 1][0])[(d & 1) * 16 + dwc] = pk;  \
      }                                                                    \
    }                                                                      \
  } while (0)

  // prologue: tile 0 into buffer 0
  LOADREGS(0);
  WRITELDS(0);
  __syncthreads();

  int buf = 0;
  for (int kt = 0; kt < nt; ++kt) {
    const bool more = (kt + 1 < nt);
    if (more) LOADREGS(kt + 1);   // issue global loads; consumed after compute

    __builtin_amdgcn_s_setprio(1);
#pragma unroll
    for (int hh = 0; hh < 2; ++hh) {
      // S^T = K Q^T for 32-key half hh
      f32x4 acc0 = (f32x4){0.f, 0.f, 0.f, 0.f};
      f32x4 acc1 = acc0;
#pragma unroll
      for (int kk = 0; kk < 4; ++kk) {
        bf16x8 a0 = *(const bf16x8*)&Ks[buf][hh * 32 + l15][kk * 32 + quad * 8];
        bf16x8 a1 = *(const bf16x8*)&Ks[buf][hh * 32 + 16 + l15][kk * 32 + quad * 8];
        acc0 = __builtin_amdgcn_mfma_f32_16x16x32_bf16(a0, bq[kk], acc0, 0, 0, 0);
        acc1 = __builtin_amdgcn_mfma_f32_16x16x32_bf16(a1, bq[kk], acc1, 0, 0, 0);
      }

      const uint32_t mword = mw[buf][w * 16 + l15][hh];
      bf16x8 bp;
      float ps = 0.f;
#pragma unroll
      for (int r = 0; r < 4; ++r) {
        const float p0 = ((mword >> (quad * 4 + r)) & 1u) ? __builtin_amdgcn_exp2f(acc0[r]) : 0.f;
        const float p1 = ((mword >> (16 + quad * 4 + r)) & 1u) ? __builtin_amdgcn_exp2f(acc1[r]) : 0.f;
        ps += p0 + p1;
        bp[r] = (short)f2bf(p0);
        bp[4 + r] = (short)f2bf(p1);
      }
      l_lane += ps;

      // O^T += V^T P^T
#pragma unroll
      for (int f = 0; f < 8; ++f) {
        const int d = f * 16 + l15;
        bf16x8 av = *(const bf16x8*)&Vt[buf][hh][d >> 1][(d & 1) * 32 + quad * 8];
        O[f] = __builtin_amdgcn_mfma_f32_16x16x32_bf16(av, bp, O[f], 0, 0, 0);
      }
    }
    __builtin_amdgcn_s_setprio(0);

    if (more) WRITELDS(buf ^ 1);   // other buffer: safe vs concurrent compute(buf)
    __syncthreads();
    buf ^= 1;
  }
#undef LOADREGS
#undef WRITELDS

  l_lane += __shfl_xor(l_lane, 16);
  l_lane += __shfl_xor(l_lane, 32);
  const float rl = 1.0f / l_lane;

  unsigned short* orow = ctx + ((size_t)(b * Lq + q0 + w * 16 + l15)) * Dm + h * DH;
#pragma unroll
  for (int f = 0; f < 8; ++f) {
    ushort4 o4;
    o4.x = f2bf(O[f][0] * rl);
    o4.y = f2bf(O[f][1] * rl);
    o4.z = f2bf(O[f][2] * rl);
    o4.w = f2bf(O[f][3] * rl);
    *(ushort4*)(orow + f * 16 + quad * 4) = o4;
  }
}

// ---------------------------------------------------------------------------
extern "C" void kernel_launch(void* const* d_in, const int* in_sizes, int n_in,
                              void* d_out, int out_size, void* d_ws, size_t ws_size,
                              hipStream_t stream) {
  const float* hs  = (const float*)d_in[0];
  const float* rel = (const float*)d_in[1];
  const float* Wqr = (const float*)d_in[2];
  const float* Wkr = (const float*)d_in[3];
  const float* Wq  = (const float*)d_in[4];
  const float* Wk  = (const float*)d_in[5];
  const float* Wv  = (const float*)d_in[6];
  const float* Wo  = (const float*)d_in[7];
  float* out = (float*)d_out;

  const int M = Bb * Lq;   // 4096
  const int ND = Dm * Dm;
  char* ws = (char*)d_ws;
  size_t off = 0;
  float* qrel = (float*)(ws + off); off += (size_t)M * DREL * 4;
  float* krel = (float*)(ws + off); off += (size_t)M * DREL * 4;
  uint32_t* maskb = (uint32_t*)(ws + off); off += (size_t)M * (Lq / 32) * 4;
  float* partq = (float*)(ws + off); off += (size_t)RKS * M * DREL * 4;
  float* partk = (float*)(ws + off); off += (size_t)RKS * M * DREL * 4;
  // bf16 staging region; Sbuf (B*L*L fp32 = 33.5 MB) is ALIASED onto its head:
  // Sbuf is consumed by relselect before any bf16 buffer is written (in-order stream).
  float* Sbuf = (float*)(ws + off);
  unsigned short* hsb  = (unsigned short*)(ws + off); off += (size_t)M * Dm * 2;
  unsigned short* qkvb = (unsigned short*)(ws + off); off += (size_t)M * 3 * Dm * 2;
  unsigned short* ctxb = (unsigned short*)(ws + off); off += (size_t)M * Dm * 2;
  unsigned short* Wqkvo = (unsigned short*)(ws + off); off += (size_t)4 * ND * 2;  // Wq,Wk,Wv,Wo contiguous

  const dim3 blk(256);
  const int hsN8 = M * Dm / 8;
  const float QSCALE = 0.08838834764831845f * 1.4426950408889634f;  // DH^-0.5 * log2(e)

  // rel pipeline: fp32-exact projections -> dense triangular scores -> wave select
  relproj2<<<dim3(RKS, M / 128, 2), blk, 0, stream>>>(rel, Wqr, Wkr, partq, partk, M);
  relreduce<<<(M * DREL / 4 + 255) / 256, blk, 0, stream>>>(partq, partk, qrel, krel, M * DREL / 4);
  relscore<<<dim3(Lq / 128, Lq / 128, Bb), blk, 0, stream>>>(qrel, krel, Sbuf);
  relselect<<<M / 4, blk, 0, stream>>>(Sbuf, maskb);

  // bf16 conversions (overwrite Sbuf region only after relselect has consumed it)
  conv_bf16<<<(hsN8 + 255) / 256, blk, 0, stream>>>(hs, hsb, hsN8, 1.0f);
  conv_bf16_w4<<<dim3(ND / 8 / 256, 4), blk, 0, stream>>>(Wq, Wk, Wv, Wo, Wqkvo, QSCALE);

  // fused QKV projection (256^2 deep-pipelined bf16 MFMA): C[M, 3*Dm]
  gemm256<true><<<dim3((M / 256) * (3 * Dm / 256)), dim3(512), 0, stream>>>(
      hsb, Wqkvo, qkvb, M, 3 * Dm, Dm);

  // flash attention v3
  attn_flash3<<<dim3(Lq / ATQ, Hh, Bb), dim3(512), 0, stream>>>(qkvb, maskb, ctxb);

  // O projection -> fp32 out
  gemm256<false><<<dim3((M / 256) * (Dm / 256)), dim3(512), 0, stream>>>(
      ctxb, Wqkvo + (size_t)3 * ND, out, M, Dm, Dm);
}

// Round 3
// 482.734 us; speedup vs baseline: 1.2385x; 1.0147x over previous
//
#include <hip/hip_runtime.h>
#include <math.h>
#include <stdint.h>

// Problem constants (match reference)
#define Bb 2
#define Lq 2048
#define Dm 2048
#define Hh 16
#define DH 128
#define DREL 64
#define KTOP 512   // 0.25 * L

#define NEG_INF (-__builtin_huge_valf())

typedef __attribute__((ext_vector_type(8))) short bf16x8;   // 8 bf16 (4 VGPRs)
typedef __attribute__((ext_vector_type(4))) float f32x4;

static __device__ __forceinline__ unsigned short f2bf(float f) {
  unsigned int u = __float_as_uint(f);
  u += 0x7fffu + ((u >> 16) & 1u);   // RNE
  return (unsigned short)(u >> 16);
}

// async global->LDS, 16B per lane; LDS dest = wave-uniform base + lane*16
static __device__ __forceinline__ void gload16(const void* g, void* lds) {
  __builtin_amdgcn_global_load_lds(
      (const __attribute__((address_space(1))) uint32_t*)(uintptr_t)g,
      (__attribute__((address_space(3))) uint32_t*)(uint32_t)(uintptr_t)lds,
      16, 0, 0);
}

// ---------------------------------------------------------------------------
// fp32 -> bf16 elementwise with optional scale (n8 = n/8)
// ---------------------------------------------------------------------------
__global__ __launch_bounds__(256) void conv_bf16(const float* __restrict__ in,
                                                 unsigned short* __restrict__ out,
                                                 int n8, float scale) {
  const int i = blockIdx.x * 256 + threadIdx.x;
  if (i >= n8) return;
  const float4 f0 = ((const float4*)in)[2 * i];
  const float4 f1 = ((const float4*)in)[2 * i + 1];
  bf16x8 o;
  o[0] = (short)f2bf(f0.x * scale); o[1] = (short)f2bf(f0.y * scale);
  o[2] = (short)f2bf(f0.z * scale); o[3] = (short)f2bf(f0.w * scale);
  o[4] = (short)f2bf(f1.x * scale); o[5] = (short)f2bf(f1.y * scale);
  o[6] = (short)f2bf(f1.z * scale); o[7] = (short)f2bf(f1.w * scale);
  *(bf16x8*)(out + 8 * (size_t)i) = o;
}

// 4 weight matrices -> bf16, one launch (blockIdx.y selects); w0 gets scale s0.
__global__ __launch_bounds__(256) void conv_bf16_w4(const float* __restrict__ w0,
                                                    const float* __restrict__ w1,
                                                    const float* __restrict__ w2,
                                                    const float* __restrict__ w3,
                                                    unsigned short* __restrict__ out,
                                                    float s0) {
  const int sel = blockIdx.y;
  const float* in = (sel == 0) ? w0 : (sel == 1) ? w1 : (sel == 2) ? w2 : w3;
  const float scale = (sel == 0) ? s0 : 1.0f;
  const int i = blockIdx.x * 256 + threadIdx.x;   // grid.x = ND/8/256 exact
  const float4 f0 = ((const float4*)in)[2 * i];
  const float4 f1 = ((const float4*)in)[2 * i + 1];
  bf16x8 o;
  o[0] = (short)f2bf(f0.x * scale); o[1] = (short)f2bf(f0.y * scale);
  o[2] = (short)f2bf(f0.z * scale); o[3] = (short)f2bf(f0.w * scale);
  o[4] = (short)f2bf(f1.x * scale); o[5] = (short)f2bf(f1.y * scale);
  o[6] = (short)f2bf(f1.z * scale); o[7] = (short)f2bf(f1.w * scale);
  *(bf16x8*)(out + (size_t)sel * Dm * Dm + 8 * (size_t)i) = o;
}

// ---------------------------------------------------------------------------
// 256x256 8-wave counted-vmcnt pipelined bf16 GEMM (T1+T2+T3/T4+T5).
// C[M,N] = A[M,K] @ W[N,K]^T, fp32 accum. M%256==0, N%256==0, K%64==0, K/64>=3.
//
// LDS: [buf][rowhalf][ks][128][32] per operand = 8KB subtiles; one gload16
// call-site (512 thr x 16B) fills exactly one subtile. 128 KiB total.
//
// Schedule per K-tile group (4 phases, tile t in buf=t&1, staging into same
// region it frees):
//   ph0: ds A[ks0](8) B[ks0][n01](2) | stage B.ks1(t+1)->buf^1 | bar | 16 MFMA | bar
//   ph1: ds B[ks0][n23](2)           | stage A.ks0(t+2)->buf   | vmcnt(10) bar | 16 MFMA | bar
//   ph2: ds A[ks1](8) B[ks1][n01](2) | stage B.ks0(t+2)->buf   | bar | 16 MFMA | bar
//   ph3: ds B[ks1][n23](2)           | stage A.ks1(t+2)->buf   | vmcnt(10) bar | 16 MFMA | bar
// Write-after-read: each staged subtile's last ds_read is in the phase before
// its stage (A.ks0 read ph0 only; B.ks0 ph0+ph1; A.ks1 ph2; B.ks1 ph2+ph3;
// buf^1's B.ks1 was read in group t-1). Read-after-write: vmcnt(10) = exactly
// the 10 loads issued after the guarded subtile pair (stream: 2 loads/phase),
// verified including the prologue (14 loads, vmcnt(6)). Never vmcnt(0) in loop.
// ---------------------------------------------------------------------------
template <bool BF16OUT>
__global__ __launch_bounds__(512, 2) void gemm256(const unsigned short* __restrict__ A,
                                                  const unsigned short* __restrict__ W,
                                                  void* __restrict__ Cv,
                                                  int M, int N, int Kd) {
  __shared__ unsigned short As[2][2][2][128][32];   // 64 KiB
  __shared__ unsigned short Bs[2][2][2][128][32];   // 64 KiB

  const int tid = threadIdx.x;
  const int w = tid >> 6;
  const int lane = tid & 63;
  const int l15 = lane & 15;
  const int quad = lane >> 4;
  const int wm = w >> 2;        // 0..1 -> row half
  const int wn = w & 3;         // 0..3 -> 64-col slice

  // T1: XCD column-chunk mapping (each XCD owns a few B-panel columns -> L2-fit)
  const int gy = M >> 8;
  const int nwg = gy * (N >> 8);
  const int cpx = nwg >> 3;                 // nwg % 8 == 0 for our shapes
  const int bid = (int)blockIdx.x;
  const int lin = (bid & 7) * cpx + (bid >> 3);
  const int by = lin % gy, bx = lin / gy;
  const int m0 = by * 256, n0 = bx * 256;

  // staging source (per lane). Within a subtile call-site:
  //   row r = w*16 + (lane>>2), phys 16B-slot = lane&3.
  // Read swizzle is phys = quad ^ ((r>>1)&3); inverse on the global source:
  //   logical slot = (lane&3) ^ ((r>>1)&3) = (lane&3) ^ ((lane>>3)&3).
  const int srow = w * 16 + (lane >> 2);
  const int sslot = (lane & 3) ^ ((lane >> 3) & 3);
  const unsigned short* aB = A + (size_t)(m0 + srow) * Kd + sslot * 8;
  const unsigned short* bB = W + (size_t)(n0 + srow) * Kd + sslot * 8;
  const size_t hstep = (size_t)128 * Kd;

  f32x4 acc[8][4];
#pragma unroll
  for (int i = 0; i < 8; ++i)
#pragma unroll
    for (int j = 0; j < 4; ++j) acc[i][j] = (f32x4){0.f, 0.f, 0.f, 0.f};

  bf16x8 af[8], bfr[2];
  const int rswz = (quad ^ ((l15 >> 1) & 3)) * 8;   // phys slot -> element offset

#define ST_A(BUF, S, T)                                                     \
  do {                                                                      \
    const size_t ko = (size_t)(T) * 64 + (S) * 32;                          \
    gload16(aB + ko, &As[BUF][0][S][w * 16][0]);                            \
    gload16(aB + hstep + ko, &As[BUF][1][S][w * 16][0]);                    \
  } while (0)

#define ST_B(BUF, S, T)                                                     \
  do {                                                                      \
    const size_t ko = (size_t)(T) * 64 + (S) * 32;                          \
    gload16(bB + ko, &Bs[BUF][0][S][w * 16][0]);                            \
    gload16(bB + hstep + ko, &Bs[BUF][1][S][w * 16][0]);                    \
  } while (0)

#define LD_A(BUF, S)                                                        \
  _Pragma("unroll") for (int mi = 0; mi < 8; ++mi)                          \
      af[mi] = *(const bf16x8*)&As[BUF][wm][S][mi * 16 + l15][rswz];

#define LD_B(BUF, S, NP)                                                    \
  _Pragma("unroll") for (int ni = 0; ni < 2; ++ni)                          \
      bfr[ni] = *(const bf16x8*)&Bs[BUF][wn >> 1][S]                        \
          [(wn & 1) * 64 + ((NP) * 2 + ni) * 16 + l15][rswz];

#define MFMA16(NP)                                                          \
  do {                                                                      \
    __builtin_amdgcn_s_setprio(1);                                          \
    _Pragma("unroll") for (int mi = 0; mi < 8; ++mi)                        \
        _Pragma("unroll") for (int ni = 0; ni < 2; ++ni)                    \
            acc[mi][(NP) * 2 + ni] = __builtin_amdgcn_mfma_f32_16x16x32_bf16( \
                af[mi], bfr[ni], acc[mi][(NP) * 2 + ni], 0, 0, 0);          \
    __builtin_amdgcn_s_setprio(0);                                          \
  } while (0)

#define SBAR()        asm volatile("s_barrier" ::: "memory")
#define WAITBAR(N)    asm volatile("s_waitcnt vmcnt(" #N ")\ns_barrier" ::: "memory")

  // prologue: tile 0 fully + tile 1 minus B.ks1 (14 loads); need tile 0 (first 8)
  ST_A(0, 0, 0); ST_B(0, 0, 0); ST_A(0, 1, 0); ST_B(0, 1, 0);
  ST_A(1, 0, 1); ST_B(1, 0, 1); ST_A(1, 1, 1);
  WAITBAR(6);

  const int nt = Kd >> 6;
  int buf = 0;
  for (int t = 0; t < nt - 2; ++t) {
    // ph0: ks0 x n01
    LD_A(buf, 0);
    LD_B(buf, 0, 0);
    ST_B(buf ^ 1, 1, t + 1);
    SBAR();
    MFMA16(0);
    SBAR();
    // ph1: ks0 x n23
    LD_B(buf, 0, 1);
    ST_A(buf, 0, t + 2);
    WAITBAR(10);
    MFMA16(1);
    SBAR();
    // ph2: ks1 x n01
    LD_A(buf, 1);
    LD_B(buf, 1, 0);
    ST_B(buf, 0, t + 2);
    SBAR();
    MFMA16(0);
    SBAR();
    // ph3: ks1 x n23
    LD_B(buf, 1, 1);
    ST_A(buf, 1, t + 2);
    WAITBAR(10);
    MFMA16(1);
    SBAR();
    buf ^= 1;
  }

  // epilogue: last missing subtile, single drain, final 2 tiles barrier-free
  ST_B(buf ^ 1, 1, nt - 1);
  WAITBAR(0);
  for (int g = 0; g < 2; ++g) {
    LD_A(buf, 0); LD_B(buf, 0, 0); MFMA16(0);
    LD_B(buf, 0, 1);               MFMA16(1);
    LD_A(buf, 1); LD_B(buf, 1, 0); MFMA16(0);
    LD_B(buf, 1, 1);               MFMA16(1);
    buf ^= 1;
  }
#undef ST_A
#undef ST_B
#undef LD_A
#undef LD_B
#undef MFMA16
#undef SBAR
#undef WAITBAR

#pragma unroll
  for (int im = 0; im < 8; ++im) {
#pragma unroll
    for (int in = 0; in < 4; ++in) {
      const int col = n0 + wn * 64 + in * 16 + l15;
#pragma unroll
      for (int r = 0; r < 4; ++r) {
        const int row = m0 + wm * 128 + im * 16 + quad * 4 + r;
        if (BF16OUT)
          ((unsigned short*)Cv)[(size_t)row * N + col] = f2bf(acc[im][in][r]);
        else
          ((float*)Cv)[(size_t)row * N + col] = acc[im][in][r];
      }
    }
  }
}

// ---------------------------------------------------------------------------
// Split-K fp32 rel projection, q and k fused via blockIdx.z.
// ---------------------------------------------------------------------------
#define RKS 8
__global__ __launch_bounds__(256) void relproj2(const float* __restrict__ A,
                                                const float* __restrict__ Wqr,
                                                const float* __restrict__ Wkr,
                                                float* __restrict__ partq,
                                                float* __restrict__ partk, int M) {
  const float* W = blockIdx.z ? Wkr : Wqr;
  float* part = blockIdx.z ? partk : partq;
  __shared__ float As[16][128];
  __shared__ float Bs[16][64];
  const int ks = blockIdx.x;
  const int m0 = blockIdx.y * 128;
  const int tid = threadIdx.x;
  const int tx = tid & 15;
  const int ty = tid >> 4;
  const int lr = tid >> 1, lk = (tid & 1) * 8;
  const int wr = tid >> 2, wk = (tid & 3) * 4;

  float acc[8][4];
#pragma unroll
  for (int i = 0; i < 8; ++i)
#pragma unroll
    for (int j = 0; j < 4; ++j) acc[i][j] = 0.f;

  const int k00 = ks * (Dm / RKS);
  for (int k0 = k00; k0 < k00 + Dm / RKS; k0 += 16) {
    {
      const float* ap = A + (size_t)(m0 + lr) * Dm + k0 + lk;
      float4 a0 = *(const float4*)(ap);
      float4 a1 = *(const float4*)(ap + 4);
      As[lk + 0][lr] = a0.x; As[lk + 1][lr] = a0.y;
      As[lk + 2][lr] = a0.z; As[lk + 3][lr] = a0.w;
      As[lk + 4][lr] = a1.x; As[lk + 5][lr] = a1.y;
      As[lk + 6][lr] = a1.z; As[lk + 7][lr] = a1.w;
    }
    {
      const float* bp = W + (size_t)wr * Dm + k0 + wk;
      float4 b0 = *(const float4*)(bp);
      Bs[wk + 0][wr] = b0.x; Bs[wk + 1][wr] = b0.y;
      Bs[wk + 2][wr] = b0.z; Bs[wk + 3][wr] = b0.w;
    }
    __syncthreads();
#pragma unroll
    for (int kk = 0; kk < 16; ++kk) {
      float af[8], bf[4];
#pragma unroll
      for (int i = 0; i < 8; ++i) af[i] = As[kk][ty * 8 + i];
#pragma unroll
      for (int j = 0; j < 4; ++j) bf[j] = Bs[kk][tx * 4 + j];
#pragma unroll
      for (int i = 0; i < 8; ++i)
#pragma unroll
        for (int j = 0; j < 4; ++j) acc[i][j] += af[i] * bf[j];
    }
    __syncthreads();
  }

#pragma unroll
  for (int i = 0; i < 8; ++i) {
    float* pp = part + ((size_t)ks * M + m0 + ty * 8 + i) * DREL + tx * 4;
    *(float4*)pp = make_float4(acc[i][0], acc[i][1], acc[i][2], acc[i][3]);
  }
}

__global__ __launch_bounds__(256) void relreduce(const float* __restrict__ pq,
                                                 const float* __restrict__ pk,
                                                 float* __restrict__ qrel,
                                                 float* __restrict__ krel, int n4) {
  const int i = blockIdx.x * 256 + threadIdx.x;
  if (i >= n4) return;
  float4 sq = make_float4(0, 0, 0, 0), sk = sq;
  for (int s = 0; s < RKS; ++s) {
    float4 a = ((const float4*)pq)[(size_t)s * n4 + i];
    float4 b = ((const float4*)pk)[(size_t)s * n4 + i];
    sq.x += a.x; sq.y += a.y; sq.z += a.z; sq.w += a.w;
    sk.x += b.x; sk.y += b.y; sk.z += b.z; sk.w += b.w;
  }
  ((float4*)qrel)[i] = sq;
  ((float4*)krel)[i] = sk;
}

// ---------------------------------------------------------------------------
// Dense triangular rel-score GEMM: S[b][q][j] = (qrel[b,q,:]·krel[b,j,:])*DREL^-0.5
// ---------------------------------------------------------------------------
__global__ __launch_bounds__(256) void relscore(const float* __restrict__ qrel,
                                                const float* __restrict__ krel,
                                                float* __restrict__ S) {
  const int jt = blockIdx.x, qt = blockIdx.y, b = blockIdx.z;
  if (jt > qt) return;
  __shared__ float As[16][128];
  __shared__ float Bs[16][128];
  const int tid = threadIdx.x;
  const int q0 = qt * 128, j0 = jt * 128;
  const int tx = tid & 15, ty = tid >> 4;
  const int lr = tid >> 1, lk = (tid & 1) * 8;
  const float* Ab = qrel + (size_t)b * Lq * DREL;
  const float* Kb = krel + (size_t)b * Lq * DREL;

  float acc[8][8];
#pragma unroll
  for (int i = 0; i < 8; ++i)
#pragma unroll
    for (int j = 0; j < 8; ++j) acc[i][j] = 0.f;

  for (int k0 = 0; k0 < DREL; k0 += 16) {
    {
      const float* ap = Ab + (size_t)(q0 + lr) * DREL + k0 + lk;
      float4 a0 = *(const float4*)(ap);
      float4 a1 = *(const float4*)(ap + 4);
      As[lk + 0][lr] = a0.x; As[lk + 1][lr] = a0.y;
      As[lk + 2][lr] = a0.z; As[lk + 3][lr] = a0.w;
      As[lk + 4][lr] = a1.x; As[lk + 5][lr] = a1.y;
      As[lk + 6][lr] = a1.z; As[lk + 7][lr] = a1.w;
    }
    {
      const float* bp = Kb + (size_t)(j0 + lr) * DREL + k0 + lk;
      float4 b0 = *(const float4*)(bp);
      float4 b1 = *(const float4*)(bp + 4);
      Bs[lk + 0][lr] = b0.x; Bs[lk + 1][lr] = b0.y;
      Bs[lk + 2][lr] = b0.z; Bs[lk + 3][lr] = b0.w;
      Bs[lk + 4][lr] = b1.x; Bs[lk + 5][lr] = b1.y;
      Bs[lk + 6][lr] = b1.z; Bs[lk + 7][lr] = b1.w;
    }
    __syncthreads();
#pragma unroll
    for (int kk = 0; kk < 16; ++kk) {
      float af[8], bf[8];
#pragma unroll
      for (int i = 0; i < 8; ++i) af[i] = As[kk][ty * 8 + i];
#pragma unroll
      for (int j = 0; j < 8; ++j) bf[j] = Bs[kk][tx * 8 + j];
#pragma unroll
      for (int i = 0; i < 8; ++i)
#pragma unroll
        for (int j = 0; j < 8; ++j) acc[i][j] += af[i] * bf[j];
    }
    __syncthreads();
  }

  const float sc = 0.125f;  // DREL^-0.5
#pragma unroll
  for (int i = 0; i < 8; ++i) {
    float* cp = S + ((size_t)b * Lq + q0 + ty * 8 + i) * Lq + j0 + tx * 8;
    ((float4*)cp)[0] = make_float4(acc[i][0] * sc, acc[i][1] * sc, acc[i][2] * sc, acc[i][3] * sc);
    ((float4*)cp)[1] = make_float4(acc[i][4] * sc, acc[i][5] * sc, acc[i][6] * sc, acc[i][7] * sc);
  }
}

// ---------------------------------------------------------------------------
// Wave-per-row exact top-K select + mask emission, all in registers.
// ---------------------------------------------------------------------------
__global__ __launch_bounds__(256) void relselect(const float* __restrict__ S,
                                                 uint32_t* __restrict__ mask) {
  const int w = threadIdx.x >> 6;
  const int lane = threadIdx.x & 63;
  const int ridx = blockIdx.x * 4 + w;      // = b*Lq + qi
  const int qi = ridx & (Lq - 1);
  const int n = qi + 1;
  const float* srow = S + (size_t)ridx * Lq;

  uint32_t keys[32];
#pragma unroll
  for (int t = 0; t < 32; ++t) {
    const int j = t * 64 + lane;
    const uint32_t u = __float_as_uint(srow[j]);
    const uint32_t k = (u & 0x80000000u) ? ~u : (u | 0x80000000u);
    keys[t] = (j < n) ? k : 0u;   // 0 never matches any candidate prefix
  }

  uint32_t kth = 0u;
  if (n > KTOP) {
    uint32_t pref = 0u;
    int rem = KTOP;
    for (int bit = 31; bit >= 0; --bit) {
      const uint32_t cand = pref | (1u << bit);
      const uint32_t lim = 1u << bit;
      int c = 0;
#pragma unroll
      for (int t = 0; t < 32; ++t) c += ((keys[t] ^ cand) < lim) ? 1 : 0;
      c += __shfl_xor(c, 1);
      c += __shfl_xor(c, 2);
      c += __shfl_xor(c, 4);
      c += __shfl_xor(c, 8);
      c += __shfl_xor(c, 16);
      c += __shfl_xor(c, 32);
      if (c >= rem) pref = cand;
      else rem -= c;
    }
    kth = pref;
  }

  uint32_t* mrow = mask + (size_t)ridx * (Lq / 32);
#pragma unroll
  for (int t = 0; t < 32; ++t) {
    const int j = t * 64 + lane;
    const bool ok = (j < n) && (keys[t] >= kth || j == qi);  // kth=0 -> causal-only
    const unsigned long long bal = __ballot(ok);
    if (lane == 0) {
      mrow[2 * t] = (uint32_t)bal;
      mrow[2 * t + 1] = (uint32_t)(bal >> 32);
    }
  }
}

// ---------------------------------------------------------------------------
// Flash attention v3: TK=64 tiles, double-buffered LDS with reg-staged
// async split (T14), one barrier per tile, setprio around MFMA cluster (T5).
// Q is pre-scaled by DH^-0.5*log2(e) at weight-conversion time.
// Reads fused QKV buffer with row stride 3*Dm (q at +0, k at +2048, v at +4096).
// ---------------------------------------------------------------------------
#define ATQ 128
#define TK 64
__global__ __launch_bounds__(512, 4) void attn_flash3(const unsigned short* __restrict__ qkv,
                                                      const uint32_t* __restrict__ mask,
                                                      unsigned short* __restrict__ ctx) {
  __shared__ unsigned short Ks[2][TK][136];      // 34816 B
  __shared__ unsigned short Vt[2][2][64][72];    // 36864 B  [buf][half][d>>1][(d&1)*32+slot]
  __shared__ uint32_t mw[2][ATQ][2];             //  2048 B

  // z=0: heavy-first; z=1: light-first -> co-resident pairs (id, id+256) balance
  const int qt = (blockIdx.z == 0) ? ((Lq / ATQ) - 1 - (int)blockIdx.x) : (int)blockIdx.x;
  const int h = blockIdx.y;
  const int b = blockIdx.z;
  const int tid = threadIdx.x;
  const int w = tid >> 6;          // wave 0..7
  const int lane = tid & 63;
  const int l15 = lane & 15;
  const int quad = lane >> 4;
  const int q0 = qt * ATQ;
  const int STR = 3 * Dm;

  const unsigned short* kbp = qkv + 2048;
  const unsigned short* vbp = qkv + 4096;

  // Q fragment (already scaled by DH^-0.5*log2e via Wq conversion)
  const int myq = q0 + w * 16 + l15;
  const unsigned short* qrow = qkv + (size_t)(b * Lq + myq) * STR + h * DH;
  bf16x8 bq[4];
#pragma unroll
  for (int kk = 0; kk < 4; ++kk) bq[kk] = *(const bf16x8*)(qrow + kk * 32 + quad * 8);

  f32x4 O[8];  // O^T: O[f][r] = ctx[q=l15][f*16 + quad*4 + r]
#pragma unroll
  for (int f = 0; f < 8; ++f) O[f] = (f32x4){0.f, 0.f, 0.f, 0.f};
  float l_lane = 0.f;

  const int nt = (q0 + ATQ) / TK;   // = 2*qt + 2

  // staging geometry: waves 0-3 stage K + mask, waves 4-7 stage V
  const int skey = (tid & 255) >> 2;     // K: key 0..63
  const int scg  = tid & 3;              // K: dim group of 32
  const int mq   = (tid & 255) >> 1;     // mask: q row 0..127
  const int msel = tid & 1;
  const int tv = tid - 256;
  const int vkp = tv & 31;               // V: key pair 0..31
  const int vdg = (tv >> 5) & 7;         // V: dim group of 16
  const int vhalf = vkp >> 4;
  const int vkp16 = vkp & 15;
  const int dwc = ((vkp16 >> 1) & 3) * 4 + (vkp16 >> 3) * 2 + (vkp16 & 1);

  const uint32_t* mrow_base = mask + (size_t)(b * Lq + q0 + mq) * (Lq / 32) + msel;
  const unsigned short* krow_base = kbp + (size_t)(b * Lq + skey) * STR + h * DH + scg * 32;
  const unsigned short* vrow_base = vbp + (size_t)(b * Lq + 2 * vkp) * STR + h * DH + vdg * 16;

  bf16x8 r0, r1, r2, r3;
  uint32_t mreg = 0;

#define LOADREGS(KT)                                                       \
  do {                                                                     \
    const int kbase_ = (KT) * TK;                                          \
    if (tid < 256) {                                                       \
      const unsigned short* kr = krow_base + (size_t)kbase_ * STR;         \
      r0 = *(const bf16x8*)(kr);                                           \
      r1 = *(const bf16x8*)(kr + 8);                                       \
      r2 = *(const bf16x8*)(kr + 16);                                      \
      r3 = *(const bf16x8*)(kr + 24);                                      \
      mreg = mrow_base[(KT) * 2];                                          \
    } else {                                                               \
      const unsigned short* vr = vrow_base + (size_t)kbase_ * STR;         \
      r0 = *(const bf16x8*)(vr);                                           \
      r1 = *(const bf16x8*)(vr + 8);                                       \
      r2 = *(const bf16x8*)(vr + STR);                                     \
      r3 = *(const bf16x8*)(vr + STR + 8);                                 \
    }                                                                      \
  } while (0)

#define WRITELDS(BUF)                                                      \
  do {                                                                     \
    if (tid < 256) {                                                       \
      *(bf16x8*)&Ks[BUF][skey][scg * 32 + 0]  = r0;                        \
      *(bf16x8*)&Ks[BUF][skey][scg * 32 + 8]  = r1;                        \
      *(bf16x8*)&Ks[BUF][skey][scg * 32 + 16] = r2;                        \
      *(bf16x8*)&Ks[BUF][skey][scg * 32 + 24] = r3;                        \
      mw[BUF][mq][msel] = mreg;                                            \
    } else {                                                               \
      _Pragma("unroll") for (int i = 0; i < 8; ++i) {                      \
        const int d = vdg * 16 + i;                                        \
        const uint32_t pk = (uint32_t)(unsigned short)r0[i] |              \
                            ((uint32_t)(unsigned short)r2[i] << 16);       \
        ((uint32_t*)&Vt[BUF][vhalf][d >> 1][0])[(d & 1) * 16 + dwc] = pk;  \
      }                                                                    \
      _Pragma("unroll") for (int i = 0; i < 8; ++i) {                      \
        const int d = vdg * 16 + 8 + i;                                    \
        const uint32_t pk = (uint32_t)(unsigned short)r1[i] |              \
                            ((uint32_t)(unsigned short)r3[i] << 16);       \
        ((uint32_t*)&Vt[BUF][vhalf][d >> 1][0])[(d & 1) * 16 + dwc] = pk;  \
      }                                                                    \
    }                                                                      \
  } while (0)

  // prologue: tile 0 into buffer 0
  LOADREGS(0);
  WRITELDS(0);
  __syncthreads();

  int buf = 0;
  for (int kt = 0; kt < nt; ++kt) {
    const bool more = (kt + 1 < nt);
    if (more) LOADREGS(kt + 1);   // issue global loads; consumed after compute

    __builtin_amdgcn_s_setprio(1);
#pragma unroll
    for (int hh = 0; hh < 2; ++hh) {
      // S^T = K Q^T for 32-key half hh
      f32x4 acc0 = (f32x4){0.f, 0.f, 0.f, 0.f};
      f32x4 acc1 = acc0;
#pragma unroll
      for (int kk = 0; kk < 4; ++kk) {
        bf16x8 a0 = *(const bf16x8*)&Ks[buf][hh * 32 + l15][kk * 32 + quad * 8];
        bf16x8 a1 = *(const bf16x8*)&Ks[buf][hh * 32 + 16 + l15][kk * 32 + quad * 8];
        acc0 = __builtin_amdgcn_mfma_f32_16x16x32_bf16(a0, bq[kk], acc0, 0, 0, 0);
        acc1 = __builtin_amdgcn_mfma_f32_16x16x32_bf16(a1, bq[kk], acc1, 0, 0, 0);
      }

      const uint32_t mword = mw[buf][w * 16 + l15][hh];
      bf16x8 bp;
      float ps = 0.f;
#pragma unroll
      for (int r = 0; r < 4; ++r) {
        const float p0 = ((mword >> (quad * 4 + r)) & 1u) ? __builtin_amdgcn_exp2f(acc0[r]) : 0.f;
        const float p1 = ((mword >> (16 + quad * 4 + r)) & 1u) ? __builtin_amdgcn_exp2f(acc1[r]) : 0.f;
        ps += p0 + p1;
        bp[r] = (short)f2bf(p0);
        bp[4 + r] = (short)f2bf(p1);
      }
      l_lane += ps;

      // O^T += V^T P^T
#pragma unroll
      for (int f = 0; f < 8; ++f) {
        const int d = f * 16 + l15;
        bf16x8 av = *(const bf16x8*)&Vt[buf][hh][d >> 1][(d & 1) * 32 + quad * 8];
        O[f] = __builtin_amdgcn_mfma_f32_16x16x32_bf16(av, bp, O[f], 0, 0, 0);
      }
    }
    __builtin_amdgcn_s_setprio(0);

    if (more) WRITELDS(buf ^ 1);   // other buffer: safe vs concurrent compute(buf)
    __syncthreads();
    buf ^= 1;
  }
#undef LOADREGS
#undef WRITELDS

  l_lane += __shfl_xor(l_lane, 16);
  l_lane += __shfl_xor(l_lane, 32);
  const float rl = 1.0f / l_lane;

  unsigned short* orow = ctx + ((size_t)(b * Lq + q0 + w * 16 + l15)) * Dm + h * DH;
#pragma unroll
  for (int f = 0; f < 8; ++f) {
    ushort4 o4;
    o4.x = f2bf(O[f][0] * rl);
    o4.y = f2bf(O[f][1] * rl);
    o4.z = f2bf(O[f][2] * rl);
    o4.w = f2bf(O[f][3] * rl);
    *(ushort4*)(orow + f * 16 + quad * 4) = o4;
  }
}

// ---------------------------------------------------------------------------
extern "C" void kernel_launch(void* const* d_in, const int* in_sizes, int n_in,
                              void* d_out, int out_size, void* d_ws, size_t ws_size,
                              hipStream_t stream) {
  const float* hs  = (const float*)d_in[0];
  const float* rel = (const float*)d_in[1];
  const float* Wqr = (const float*)d_in[2];
  const float* Wkr = (const float*)d_in[3];
  const float* Wq  = (const float*)d_in[4];
  const float* Wk  = (const float*)d_in[5];
  const float* Wv  = (const float*)d_in[6];
  const float* Wo  = (const float*)d_in[7];
  float* out = (float*)d_out;

  const int M = Bb * Lq;   // 4096
  const int ND = Dm * Dm;
  char* ws = (char*)d_ws;
  size_t off = 0;
  float* qrel = (float*)(ws + off); off += (size_t)M * DREL * 4;
  float* krel = (float*)(ws + off); off += (size_t)M * DREL * 4;
  uint32_t* maskb = (uint32_t*)(ws + off); off += (size_t)M * (Lq / 32) * 4;
  float* partq = (float*)(ws + off); off += (size_t)RKS * M * DREL * 4;
  float* partk = (float*)(ws + off); off += (size_t)RKS * M * DREL * 4;
  // bf16 staging region; Sbuf (B*L*L fp32 = 33.5 MB) is ALIASED onto its head:
  // Sbuf is consumed by relselect before any bf16 buffer is written (in-order stream).
  float* Sbuf = (float*)(ws + off);
  unsigned short* hsb  = (unsigned short*)(ws + off); off += (size_t)M * Dm * 2;
  unsigned short* qkvb = (unsigned short*)(ws + off); off += (size_t)M * 3 * Dm * 2;
  unsigned short* ctxb = (unsigned short*)(ws + off); off += (size_t)M * Dm * 2;
  unsigned short* Wqkvo = (unsigned short*)(ws + off); off += (size_t)4 * ND * 2;  // Wq,Wk,Wv,Wo contiguous

  const dim3 blk(256);
  const int hsN8 = M * Dm / 8;
  const float QSCALE = 0.08838834764831845f * 1.4426950408889634f;  // DH^-0.5 * log2(e)

  // rel pipeline: fp32-exact projections -> dense triangular scores -> wave select
  relproj2<<<dim3(RKS, M / 128, 2), blk, 0, stream>>>(rel, Wqr, Wkr, partq, partk, M);
  relreduce<<<(M * DREL / 4 + 255) / 256, blk, 0, stream>>>(partq, partk, qrel, krel, M * DREL / 4);
  relscore<<<dim3(Lq / 128, Lq / 128, Bb), blk, 0, stream>>>(qrel, krel, Sbuf);
  relselect<<<M / 4, blk, 0, stream>>>(Sbuf, maskb);

  // bf16 conversions (overwrite Sbuf region only after relselect has consumed it)
  conv_bf16<<<(hsN8 + 255) / 256, blk, 0, stream>>>(hs, hsb, hsN8, 1.0f);
  conv_bf16_w4<<<dim3(ND / 8 / 256, 4), blk, 0, stream>>>(Wq, Wk, Wv, Wo, Wqkvo, QSCALE);

  // fused QKV projection (256^2 counted-vmcnt pipelined bf16 MFMA): C[M, 3*Dm]
  gemm256<true><<<dim3((M / 256) * (3 * Dm / 256)), dim3(512), 0, stream>>>(
      hsb, Wqkvo, qkvb, M, 3 * Dm, Dm);

  // flash attention v3
  attn_flash3<<<dim3(Lq / ATQ, Hh, Bb), dim3(512), 0, stream>>>(qkvb, maskb, ctxb);

  // O projection -> fp32 out
  gemm256<false><<<dim3((M / 256) * (Dm / 256)), dim3(512), 0, stream>>>(
      ctxb, Wqkvo + (size_t)3 * ND, out, M, Dm, Dm);
}

// Round 5
// 475.433 us; speedup vs baseline: 1.2575x; 1.0154x over previous
//
#include <hip/hip_runtime.h>
#include <math.h>
#include <stdint.h>

// Problem constants (match reference)
#define Bb 2
#define Lq 2048
#define Dm 2048
#define Hh 16
#define DH 128
#define DREL 64
#define KTOP 512   // 0.25 * L

#define NEG_INF (-__builtin_huge_valf())

typedef __attribute__((ext_vector_type(8))) short bf16x8;   // 8 bf16 (4 VGPRs)
typedef __attribute__((ext_vector_type(4))) float f32x4;

static __device__ __forceinline__ unsigned short f2bf(float f) {
  unsigned int u = __float_as_uint(f);
  u += 0x7fffu + ((u >> 16) & 1u);   // RNE
  return (unsigned short)(u >> 16);
}

// async global->LDS, 16B per lane; LDS dest = wave-uniform base + lane*16
static __device__ __forceinline__ void gload16(const void* g, void* lds) {
  __builtin_amdgcn_global_load_lds(
      (const __attribute__((address_space(1))) uint32_t*)(uintptr_t)g,
      (__attribute__((address_space(3))) uint32_t*)(uint32_t)(uintptr_t)lds,
      16, 0, 0);
}

// ---------------------------------------------------------------------------
// fp32 -> bf16 elementwise with optional scale (n8 = n/8)
// ---------------------------------------------------------------------------
__global__ __launch_bounds__(256) void conv_bf16(const float* __restrict__ in,
                                                 unsigned short* __restrict__ out,
                                                 int n8, float scale) {
  const int i = blockIdx.x * 256 + threadIdx.x;
  if (i >= n8) return;
  const float4 f0 = ((const float4*)in)[2 * i];
  const float4 f1 = ((const float4*)in)[2 * i + 1];
  bf16x8 o;
  o[0] = (short)f2bf(f0.x * scale); o[1] = (short)f2bf(f0.y * scale);
  o[2] = (short)f2bf(f0.z * scale); o[3] = (short)f2bf(f0.w * scale);
  o[4] = (short)f2bf(f1.x * scale); o[5] = (short)f2bf(f1.y * scale);
  o[6] = (short)f2bf(f1.z * scale); o[7] = (short)f2bf(f1.w * scale);
  *(bf16x8*)(out + 8 * (size_t)i) = o;
}

// 4 weight matrices -> bf16, one launch (blockIdx.y selects); w0 gets scale s0.
__global__ __launch_bounds__(256) void conv_bf16_w4(const float* __restrict__ w0,
                                                    const float* __restrict__ w1,
                                                    const float* __restrict__ w2,
                                                    const float* __restrict__ w3,
                                                    unsigned short* __restrict__ out,
                                                    float s0) {
  const int sel = blockIdx.y;
  const float* in = (sel == 0) ? w0 : (sel == 1) ? w1 : (sel == 2) ? w2 : w3;
  const float scale = (sel == 0) ? s0 : 1.0f;
  const int i = blockIdx.x * 256 + threadIdx.x;   // grid.x = ND/8/256 exact
  const float4 f0 = ((const float4*)in)[2 * i];
  const float4 f1 = ((const float4*)in)[2 * i + 1];
  bf16x8 o;
  o[0] = (short)f2bf(f0.x * scale); o[1] = (short)f2bf(f0.y * scale);
  o[2] = (short)f2bf(f0.z * scale); o[3] = (short)f2bf(f0.w * scale);
  o[4] = (short)f2bf(f1.x * scale); o[5] = (short)f2bf(f1.y * scale);
  o[6] = (short)f2bf(f1.z * scale); o[7] = (short)f2bf(f1.w * scale);
  *(bf16x8*)(out + (size_t)sel * Dm * Dm + 8 * (size_t)i) = o;
}

// ---------------------------------------------------------------------------
// Pipelined bf16 GEMM, BK=32, 8 waves (2M x 4N), TRUE 2-blocks/CU residency:
// MF=4 -> BM=128 tile, 48 KiB LDS, __launch_bounds__(512,4) caps VGPR at 128
// (acc 64 + frags 24 + addressing ~25 fits). C[M,N] = A[M,K] @ W[N,K]^T.
//
// Per K-tile: { stage tile t+1 (3 gloads) -> s_waitcnt vmcnt(3)+s_barrier
//               -> 6 ds_read_b128 + 16 MFMA -> s_barrier }.
// vmcnt(3): in-order retirement means "<=3 outstanding" implies everything
// older than this iteration's own 3 stages (i.e. tile t) has landed; each
// wave waits on its OWN loads, the barrier makes it collective. Stray scratch
// VMEM ops can only cause over-waiting (safe). WAR: stage targets buf^1 =
// tile t-1's home, whose LDS reads completed before the previous end-barrier.
// vmcnt(0) only at the final tile. 2 co-resident blocks fill each other's
// stall windows (the m97 mechanism round 2/3 lacked at 1-block/CU).
// ---------------------------------------------------------------------------
template <int MF, bool BF16OUT>
__global__ __launch_bounds__(512, 4) void gemmP(const unsigned short* __restrict__ A,
                                                const unsigned short* __restrict__ W,
                                                void* __restrict__ Cv,
                                                int M, int N, int Kd) {
  constexpr int BM = MF * 32;
  __shared__ unsigned short As[2][BM][32];    // MF4: 16 KiB
  __shared__ unsigned short Bs[2][256][32];   // 32 KiB

  const int tid = threadIdx.x;
  const int lane = tid & 63;
  const int w = tid >> 6;
  const int l15 = lane & 15;
  const int quad = lane >> 4;
  const int wm = w >> 2;        // 0..1 -> row half
  const int wn = w & 3;         // 0..3 -> 64-col slice

  // T1: XCD column-chunk mapping (consecutive blocks in an XCD share B-panels)
  const int gy = M / BM;
  const int nwg = gy * (N >> 8);
  const int cpx = nwg >> 3;                 // nwg % 8 == 0 for our shapes
  const int bid = (int)blockIdx.x;
  const int lin = (bid & 7) * cpx + (bid >> 3);
  const int by = lin % gy, bx = lin / gy;
  const int m0 = by * BM, n0 = bx * 256;

  // staging: one gload16 call-site = 128 rows x 32 cols (8 KiB).
  // lane row within call-site = tid>>2, phys 16B slot = tid&3.
  // Read swizzle slot = quad ^ ((l15>>1)&3); inverse on global source:
  // logical slot = (tid&3) ^ ((row>>1)&3) = (tid&3) ^ ((tid>>3)&3).
  const int srow = tid >> 2;
  const int sslot = (tid & 3) ^ ((tid >> 3) & 3);
  const unsigned short* aB = A + (size_t)(m0 + srow) * Kd + sslot * 8;
  const unsigned short* bB = W + (size_t)(n0 + srow) * Kd + sslot * 8;
  const size_t hstep = (size_t)128 * Kd;

  f32x4 acc[MF][4];
#pragma unroll
  for (int i = 0; i < MF; ++i)
#pragma unroll
    for (int j = 0; j < 4; ++j) acc[i][j] = (f32x4){0.f, 0.f, 0.f, 0.f};

  bf16x8 af[MF], bfr[2];
  const int rswz = (quad ^ ((l15 >> 1) & 3)) * 8;   // proven 0-conflict (r3)

#define ST(BUF, T)                                                          \
  do {                                                                      \
    const size_t ko = (size_t)(T) * 32;                                     \
    gload16(aB + ko, &As[BUF][w * 16][0]);                                  \
    if constexpr (MF == 8) gload16(aB + hstep + ko, &As[BUF][(MF == 8 ? 128 : 0) + w * 16][0]); \
    gload16(bB + ko, &Bs[BUF][w * 16][0]);                                  \
    gload16(bB + hstep + ko, &Bs[BUF][128 + w * 16][0]);                    \
  } while (0)

#define LD_A(BUF)                                                           \
  _Pragma("unroll") for (int mi = 0; mi < MF; ++mi)                         \
      af[mi] = *(const bf16x8*)&As[BUF][wm * (BM / 2) + mi * 16 + l15][rswz];

#define LD_B(BUF, NP)                                                       \
  _Pragma("unroll") for (int ni = 0; ni < 2; ++ni)                          \
      bfr[ni] = *(const bf16x8*)&Bs[BUF][wn * 64 + ((NP) * 2 + ni) * 16 + l15][rswz];

#define MFMA_NP(NP)                                                         \
  do {                                                                      \
    __builtin_amdgcn_s_setprio(1);                                          \
    _Pragma("unroll") for (int mi = 0; mi < MF; ++mi)                       \
        _Pragma("unroll") for (int ni = 0; ni < 2; ++ni)                    \
            acc[mi][(NP) * 2 + ni] = __builtin_amdgcn_mfma_f32_16x16x32_bf16( \
                af[mi], bfr[ni], acc[mi][(NP) * 2 + ni], 0, 0, 0);          \
    __builtin_amdgcn_s_setprio(0);                                          \
  } while (0)

  // prologue: tile 0 -> buf 0 (no wait needed; iter 0's wait covers it)
  ST(0, 0);

  const int nt = Kd >> 5;
  int buf = 0;
  for (int t = 0; t < nt; ++t) {
    if (t + 1 < nt) {
      ST(buf ^ 1, t + 1);
      if constexpr (MF == 8)
        asm volatile("s_waitcnt vmcnt(4)\ns_barrier" ::: "memory");
      else
        asm volatile("s_waitcnt vmcnt(3)\ns_barrier" ::: "memory");
    } else {
      asm volatile("s_waitcnt vmcnt(0)\ns_barrier" ::: "memory");
    }
    LD_A(buf);
    LD_B(buf, 0);
    MFMA_NP(0);
    LD_B(buf, 1);
    MFMA_NP(1);
    asm volatile("s_barrier" ::: "memory");
    buf ^= 1;
  }
#undef ST
#undef LD_A
#undef LD_B
#undef MFMA_NP

#pragma unroll
  for (int im = 0; im < MF; ++im) {
#pragma unroll
    for (int in = 0; in < 4; ++in) {
      const int col = n0 + wn * 64 + in * 16 + l15;
#pragma unroll
      for (int r = 0; r < 4; ++r) {
        const int row = m0 + wm * (BM / 2) + im * 16 + quad * 4 + r;
        if (BF16OUT)
          ((unsigned short*)Cv)[(size_t)row * N + col] = f2bf(acc[im][in][r]);
        else
          ((float*)Cv)[(size_t)row * N + col] = acc[im][in][r];
      }
    }
  }
}

// ---------------------------------------------------------------------------
// Split-K fp32 rel projection, q and k fused via blockIdx.z.
// ---------------------------------------------------------------------------
#define RKS 8
__global__ __launch_bounds__(256) void relproj2(const float* __restrict__ A,
                                                const float* __restrict__ Wqr,
                                                const float* __restrict__ Wkr,
                                                float* __restrict__ partq,
                                                float* __restrict__ partk, int M) {
  const float* W = blockIdx.z ? Wkr : Wqr;
  float* part = blockIdx.z ? partk : partq;
  __shared__ float As[16][128];
  __shared__ float Bs[16][64];
  const int ks = blockIdx.x;
  const int m0 = blockIdx.y * 128;
  const int tid = threadIdx.x;
  const int tx = tid & 15;
  const int ty = tid >> 4;
  const int lr = tid >> 1, lk = (tid & 1) * 8;
  const int wr = tid >> 2, wk = (tid & 3) * 4;

  float acc[8][4];
#pragma unroll
  for (int i = 0; i < 8; ++i)
#pragma unroll
    for (int j = 0; j < 4; ++j) acc[i][j] = 0.f;

  const int k00 = ks * (Dm / RKS);
  for (int k0 = k00; k0 < k00 + Dm / RKS; k0 += 16) {
    {
      const float* ap = A + (size_t)(m0 + lr) * Dm + k0 + lk;
      float4 a0 = *(const float4*)(ap);
      float4 a1 = *(const float4*)(ap + 4);
      As[lk + 0][lr] = a0.x; As[lk + 1][lr] = a0.y;
      As[lk + 2][lr] = a0.z; As[lk + 3][lr] = a0.w;
      As[lk + 4][lr] = a1.x; As[lk + 5][lr] = a1.y;
      As[lk + 6][lr] = a1.z; As[lk + 7][lr] = a1.w;
    }
    {
      const float* bp = W + (size_t)wr * Dm + k0 + wk;
      float4 b0 = *(const float4*)(bp);
      Bs[wk + 0][wr] = b0.x; Bs[wk + 1][wr] = b0.y;
      Bs[wk + 2][wr] = b0.z; Bs[wk + 3][wr] = b0.w;
    }
    __syncthreads();
#pragma unroll
    for (int kk = 0; kk < 16; ++kk) {
      float af[8], bf[4];
#pragma unroll
      for (int i = 0; i < 8; ++i) af[i] = As[kk][ty * 8 + i];
#pragma unroll
      for (int j = 0; j < 4; ++j) bf[j] = Bs[kk][tx * 4 + j];
#pragma unroll
      for (int i = 0; i < 8; ++i)
#pragma unroll
        for (int j = 0; j < 4; ++j) acc[i][j] += af[i] * bf[j];
    }
    __syncthreads();
  }

#pragma unroll
  for (int i = 0; i < 8; ++i) {
    float* pp = part + ((size_t)ks * M + m0 + ty * 8 + i) * DREL + tx * 4;
    *(float4*)pp = make_float4(acc[i][0], acc[i][1], acc[i][2], acc[i][3]);
  }
}

__global__ __launch_bounds__(256) void relreduce(const float* __restrict__ pq,
                                                 const float* __restrict__ pk,
                                                 float* __restrict__ qrel,
                                                 float* __restrict__ krel, int n4) {
  const int i = blockIdx.x * 256 + threadIdx.x;
  if (i >= n4) return;
  float4 sq = make_float4(0, 0, 0, 0), sk = sq;
  for (int s = 0; s < RKS; ++s) {
    float4 a = ((const float4*)pq)[(size_t)s * n4 + i];
    float4 b = ((const float4*)pk)[(size_t)s * n4 + i];
    sq.x += a.x; sq.y += a.y; sq.z += a.z; sq.w += a.w;
    sk.x += b.x; sk.y += b.y; sk.z += b.z; sk.w += b.w;
  }
  ((float4*)qrel)[i] = sq;
  ((float4*)krel)[i] = sk;
}

// ---------------------------------------------------------------------------
// Dense triangular rel-score GEMM: S[b][q][j] = (qrel[b,q,:]·krel[b,j,:])*DREL^-0.5
// ---------------------------------------------------------------------------
__global__ __launch_bounds__(256) void relscore(const float* __restrict__ qrel,
                                                const float* __restrict__ krel,
                                                float* __restrict__ S) {
  const int jt = blockIdx.x, qt = blockIdx.y, b = blockIdx.z;
  if (jt > qt) return;
  __shared__ float As[16][128];
  __shared__ float Bs[16][128];
  const int tid = threadIdx.x;
  const int q0 = qt * 128, j0 = jt * 128;
  const int tx = tid & 15, ty = tid >> 4;
  const int lr = tid >> 1, lk = (tid & 1) * 8;
  const float* Ab = qrel + (size_t)b * Lq * DREL;
  const float* Kb = krel + (size_t)b * Lq * DREL;

  float acc[8][8];
#pragma unroll
  for (int i = 0; i < 8; ++i)
#pragma unroll
    for (int j = 0; j < 8; ++j) acc[i][j] = 0.f;

  for (int k0 = 0; k0 < DREL; k0 += 16) {
    {
      const float* ap = Ab + (size_t)(q0 + lr) * DREL + k0 + lk;
      float4 a0 = *(const float4*)(ap);
      float4 a1 = *(const float4*)(ap + 4);
      As[lk + 0][lr] = a0.x; As[lk + 1][lr] = a0.y;
      As[lk + 2][lr] = a0.z; As[lk + 3][lr] = a0.w;
      As[lk + 4][lr] = a1.x; As[lk + 5][lr] = a1.y;
      As[lk + 6][lr] = a1.z; As[lk + 7][lr] = a1.w;
    }
    {
      const float* bp = Kb + (size_t)(j0 + lr) * DREL + k0 + lk;
      float4 b0 = *(const float4*)(bp);
      float4 b1 = *(const float4*)(bp + 4);
      Bs[lk + 0][lr] = b0.x; Bs[lk + 1][lr] = b0.y;
      Bs[lk + 2][lr] = b0.z; Bs[lk + 3][lr] = b0.w;
      Bs[lk + 4][lr] = b1.x; Bs[lk + 5][lr] = b1.y;
      Bs[lk + 6][lr] = b1.z; Bs[lk + 7][lr] = b1.w;
    }
    __syncthreads();
#pragma unroll
    for (int kk = 0; kk < 16; ++kk) {
      float af[8], bf[8];
#pragma unroll
      for (int i = 0; i < 8; ++i) af[i] = As[kk][ty * 8 + i];
#pragma unroll
      for (int j = 0; j < 8; ++j) bf[j] = Bs[kk][tx * 8 + j];
#pragma unroll
      for (int i = 0; i < 8; ++i)
#pragma unroll
        for (int j = 0; j < 8; ++j) acc[i][j] += af[i] * bf[j];
    }
    __syncthreads();
  }

  const float sc = 0.125f;  // DREL^-0.5
#pragma unroll
  for (int i = 0; i < 8; ++i) {
    float* cp = S + ((size_t)b * Lq + q0 + ty * 8 + i) * Lq + j0 + tx * 8;
    ((float4*)cp)[0] = make_float4(acc[i][0] * sc, acc[i][1] * sc, acc[i][2] * sc, acc[i][3] * sc);
    ((float4*)cp)[1] = make_float4(acc[i][4] * sc, acc[i][5] * sc, acc[i][6] * sc, acc[i][7] * sc);
  }
}

// ---------------------------------------------------------------------------
// Wave-per-row exact top-K select + mask emission, all in registers.
// ---------------------------------------------------------------------------
__global__ __launch_bounds__(256) void relselect(const float* __restrict__ S,
                                                 uint32_t* __restrict__ mask) {
  const int w = threadIdx.x >> 6;
  const int lane = threadIdx.x & 63;
  const int ridx = blockIdx.x * 4 + w;      // = b*Lq + qi
  const int qi = ridx & (Lq - 1);
  const int n = qi + 1;
  const float* srow = S + (size_t)ridx * Lq;

  uint32_t keys[32];
#pragma unroll
  for (int t = 0; t < 32; ++t) {
    const int j = t * 64 + lane;
    const uint32_t u = __float_as_uint(srow[j]);
    const uint32_t k = (u & 0x80000000u) ? ~u : (u | 0x80000000u);
    keys[t] = (j < n) ? k : 0u;   // 0 never matches any candidate prefix
  }

  uint32_t kth = 0u;
  if (n > KTOP) {
    uint32_t pref = 0u;
    int rem = KTOP;
    for (int bit = 31; bit >= 0; --bit) {
      const uint32_t cand = pref | (1u << bit);
      const uint32_t lim = 1u << bit;
      int c = 0;
#pragma unroll
      for (int t = 0; t < 32; ++t) c += ((keys[t] ^ cand) < lim) ? 1 : 0;
      c += __shfl_xor(c, 1);
      c += __shfl_xor(c, 2);
      c += __shfl_xor(c, 4);
      c += __shfl_xor(c, 8);
      c += __shfl_xor(c, 16);
      c += __shfl_xor(c, 32);
      if (c >= rem) pref = cand;
      else rem -= c;
    }
    kth = pref;
  }

  uint32_t* mrow = mask + (size_t)ridx * (Lq / 32);
#pragma unroll
  for (int t = 0; t < 32; ++t) {
    const int j = t * 64 + lane;
    const bool ok = (j < n) && (keys[t] >= kth || j == qi);  // kth=0 -> causal-only
    const unsigned long long bal = __ballot(ok);
    if (lane == 0) {
      mrow[2 * t] = (uint32_t)bal;
      mrow[2 * t + 1] = (uint32_t)(bal >> 32);
    }
  }
}

// ---------------------------------------------------------------------------
// Flash attention v3: TK=64 tiles, double-buffered LDS with reg-staged
// async split (T14), one barrier per tile, setprio around MFMA cluster (T5).
// Q is pre-scaled by DH^-0.5*log2(e) at weight-conversion time.
// Reads fused QKV buffer with row stride 3*Dm (q at +0, k at +2048, v at +4096).
// ---------------------------------------------------------------------------
#define ATQ 128
#define TK 64
__global__ __launch_bounds__(512, 4) void attn_flash3(const unsigned short* __restrict__ qkv,
                                                      const uint32_t* __restrict__ mask,
                                                      unsigned short* __restrict__ ctx) {
  __shared__ unsigned short Ks[2][TK][136];      // 34816 B
  __shared__ unsigned short Vt[2][2][64][72];    // 36864 B  [buf][half][d>>1][(d&1)*32+slot]
  __shared__ uint32_t mw[2][ATQ][2];             //  2048 B

  // z=0: heavy-first; z=1: light-first -> co-resident pairs (id, id+256) balance
  const int qt = (blockIdx.z == 0) ? ((Lq / ATQ) - 1 - (int)blockIdx.x) : (int)blockIdx.x;
  const int h = blockIdx.y;
  const int b = blockIdx.z;
  const int tid = threadIdx.x;
  const int w = tid >> 6;          // wave 0..7
  const int lane = tid & 63;
  const int l15 = lane & 15;
  const int quad = lane >> 4;
  const int q0 = qt * ATQ;
  const int STR = 3 * Dm;

  const unsigned short* kbp = qkv + 2048;
  const unsigned short* vbp = qkv + 4096;

  // Q fragment (already scaled by DH^-0.5*log2e via Wq conversion)
  const int myq = q0 + w * 16 + l15;
  const unsigned short* qrow = qkv + (size_t)(b * Lq + myq) * STR + h * DH;
  bf16x8 bq[4];
#pragma unroll
  for (int kk = 0; kk < 4; ++kk) bq[kk] = *(const bf16x8*)(qrow + kk * 32 + quad * 8);

  f32x4 O[8];  // O^T: O[f][r] = ctx[q=l15][f*16 + quad*4 + r]
#pragma unroll
  for (int f = 0; f < 8; ++f) O[f] = (f32x4){0.f, 0.f, 0.f, 0.f};
  float l_lane = 0.f;

  const int nt = (q0 + ATQ) / TK;   // = 2*qt + 2

  // staging geometry: waves 0-3 stage K + mask, waves 4-7 stage V
  const int skey = (tid & 255) >> 2;     // K: key 0..63
  const int scg  = tid & 3;              // K: dim group of 32
  const int mq   = (tid & 255) >> 1;     // mask: q row 0..127
  const int msel = tid & 1;
  const int tv = tid - 256;
  const int vkp = tv & 31;               // V: key pair 0..31
  const int vdg = (tv >> 5) & 7;         // V: dim group of 16
  const int vhalf = vkp >> 4;
  const int vkp16 = vkp & 15;
  const int dwc = ((vkp16 >> 1) & 3) * 4 + (vkp16 >> 3) * 2 + (vkp16 & 1);

  const uint32_t* mrow_base = mask + (size_t)(b * Lq + q0 + mq) * (Lq / 32) + msel;
  const unsigned short* krow_base = kbp + (size_t)(b * Lq + skey) * STR + h * DH + scg * 32;
  const unsigned short* vrow_base = vbp + (size_t)(b * Lq + 2 * vkp) * STR + h * DH + vdg * 16;

  bf16x8 r0, r1, r2, r3;
  uint32_t mreg = 0;

#define LOADREGS(KT)                                                       \
  do {                                                                     \
    const int kbase_ = (KT) * TK;                                          \
    if (tid < 256) {                                                       \
      const unsigned short* kr = krow_base + (size_t)kbase_ * STR;         \
      r0 = *(const bf16x8*)(kr);                                           \
      r1 = *(const bf16x8*)(kr + 8);                                       \
      r2 = *(const bf16x8*)(kr + 16);                                      \
      r3 = *(const bf16x8*)(kr + 24);                                      \
      mreg = mrow_base[(KT) * 2];                                          \
    } else {                                                               \
      const unsigned short* vr = vrow_base + (size_t)kbase_ * STR;         \
      r0 = *(const bf16x8*)(vr);                                           \
      r1 = *(const bf16x8*)(vr + 8);                                       \
      r2 = *(const bf16x8*)(vr + STR);                                     \
      r3 = *(const bf16x8*)(vr + STR + 8);                                 \
    }                                                                      \
  } while (0)

#define WRITELDS(BUF)                                                      \
  do {                                                                     \
    if (tid < 256) {                                                       \
      *(bf16x8*)&Ks[BUF][skey][scg * 32 + 0]  = r0;                        \
      *(bf16x8*)&Ks[BUF][skey][scg * 32 + 8]  = r1;                        \
      *(bf16x8*)&Ks[BUF][skey][scg * 32 + 16] = r2;                        \
      *(bf16x8*)&Ks[BUF][skey][scg * 32 + 24] = r3;                        \
      mw[BUF][mq][msel] = mreg;                                            \
    } else {                                                               \
      _Pragma("unroll") for (int i = 0; i < 8; ++i) {                      \
        const int d = vdg * 16 + i;                                        \
        const uint32_t pk = (uint32_t)(unsigned short)r0[i] |              \
                            ((uint32_t)(unsigned short)r2[i] << 16);       \
        ((uint32_t*)&Vt[BUF][vhalf][d >> 1][0])[(d & 1) * 16 + dwc] = pk;  \
      }                                                                    \
      _Pragma("unroll") for (int i = 0; i < 8; ++i) {                      \
        const int d = vdg * 16 + 8 + i;                                    \
        const uint32_t pk = (uint32_t)(unsigned short)r1[i] |              \
                            ((uint32_t)(unsigned short)r3[i] << 16);       \
        ((uint32_t*)&Vt[BUF][vhalf][d >> 1][0])[(d & 1) * 16 + dwc] = pk;  \
      }                                                                    \
    }                                                                      \
  } while (0)

  // prologue: tile 0 into buffer 0
  LOADREGS(0);
  WRITELDS(0);
  __syncthreads();

  int buf = 0;
  for (int kt = 0; kt < nt; ++kt) {
    const bool more = (kt + 1 < nt);
    if (more) LOADREGS(kt + 1);   // issue global loads; consumed after compute

    __builtin_amdgcn_s_setprio(1);
#pragma unroll
    for (int hh = 0; hh < 2; ++hh) {
      // S^T = K Q^T for 32-key half hh
      f32x4 acc0 = (f32x4){0.f, 0.f, 0.f, 0.f};
      f32x4 acc1 = acc0;
#pragma unroll
      for (int kk = 0; kk < 4; ++kk) {
        bf16x8 a0 = *(const bf16x8*)&Ks[buf][hh * 32 + l15][kk * 32 + quad * 8];
        bf16x8 a1 = *(const bf16x8*)&Ks[buf][hh * 32 + 16 + l15][kk * 32 + quad * 8];
        acc0 = __builtin_amdgcn_mfma_f32_16x16x32_bf16(a0, bq[kk], acc0, 0, 0, 0);
        acc1 = __builtin_amdgcn_mfma_f32_16x16x32_bf16(a1, bq[kk], acc1, 0, 0, 0);
      }

      const uint32_t mword = mw[buf][w * 16 + l15][hh];
      bf16x8 bp;
      float ps = 0.f;
#pragma unroll
      for (int r = 0; r < 4; ++r) {
        const float p0 = ((mword >> (quad * 4 + r)) & 1u) ? __builtin_amdgcn_exp2f(acc0[r]) : 0.f;
        const float p1 = ((mword >> (16 + quad * 4 + r)) & 1u) ? __builtin_amdgcn_exp2f(acc1[r]) : 0.f;
        ps += p0 + p1;
        bp[r] = (short)f2bf(p0);
        bp[4 + r] = (short)f2bf(p1);
      }
      l_lane += ps;

      // O^T += V^T P^T
#pragma unroll
      for (int f = 0; f < 8; ++f) {
        const int d = f * 16 + l15;
        bf16x8 av = *(const bf16x8*)&Vt[buf][hh][d >> 1][(d & 1) * 32 + quad * 8];
        O[f] = __builtin_amdgcn_mfma_f32_16x16x32_bf16(av, bp, O[f], 0, 0, 0);
      }
    }
    __builtin_amdgcn_s_setprio(0);

    if (more) WRITELDS(buf ^ 1);   // other buffer: safe vs concurrent compute(buf)
    __syncthreads();
    buf ^= 1;
  }
#undef LOADREGS
#undef WRITELDS

  l_lane += __shfl_xor(l_lane, 16);
  l_lane += __shfl_xor(l_lane, 32);
  const float rl = 1.0f / l_lane;

  unsigned short* orow = ctx + ((size_t)(b * Lq + q0 + w * 16 + l15)) * Dm + h * DH;
#pragma unroll
  for (int f = 0; f < 8; ++f) {
    ushort4 o4;
    o4.x = f2bf(O[f][0] * rl);
    o4.y = f2bf(O[f][1] * rl);
    o4.z = f2bf(O[f][2] * rl);
    o4.w = f2bf(O[f][3] * rl);
    *(ushort4*)(orow + f * 16 + quad * 4) = o4;
  }
}

// ---------------------------------------------------------------------------
extern "C" void kernel_launch(void* const* d_in, const int* in_sizes, int n_in,
                              void* d_out, int out_size, void* d_ws, size_t ws_size,
                              hipStream_t stream) {
  const float* hs  = (const float*)d_in[0];
  const float* rel = (const float*)d_in[1];
  const float* Wqr = (const float*)d_in[2];
  const float* Wkr = (const float*)d_in[3];
  const float* Wq  = (const float*)d_in[4];
  const float* Wk  = (const float*)d_in[5];
  const float* Wv  = (const float*)d_in[6];
  const float* Wo  = (const float*)d_in[7];
  float* out = (float*)d_out;

  const int M = Bb * Lq;   // 4096
  const int ND = Dm * Dm;
  char* ws = (char*)d_ws;
  size_t off = 0;
  float* qrel = (float*)(ws + off); off += (size_t)M * DREL * 4;
  float* krel = (float*)(ws + off); off += (size_t)M * DREL * 4;
  uint32_t* maskb = (uint32_t*)(ws + off); off += (size_t)M * (Lq / 32) * 4;
  float* partq = (float*)(ws + off); off += (size_t)RKS * M * DREL * 4;
  float* partk = (float*)(ws + off); off += (size_t)RKS * M * DREL * 4;
  // bf16 staging region; Sbuf (B*L*L fp32 = 33.5 MB) is ALIASED onto its head:
  // Sbuf is consumed by relselect before any bf16 buffer is written (in-order stream).
  float* Sbuf = (float*)(ws + off);
  unsigned short* hsb  = (unsigned short*)(ws + off); off += (size_t)M * Dm * 2;
  unsigned short* qkvb = (unsigned short*)(ws + off); off += (size_t)M * 3 * Dm * 2;
  unsigned short* ctxb = (unsigned short*)(ws + off); off += (size_t)M * Dm * 2;
  unsigned short* Wqkvo = (unsigned short*)(ws + off); off += (size_t)4 * ND * 2;  // Wq,Wk,Wv,Wo contiguous

  const dim3 blk(256);
  const int hsN8 = M * Dm / 8;
  const float QSCALE = 0.08838834764831845f * 1.4426950408889634f;  // DH^-0.5 * log2(e)

  // rel pipeline: fp32-exact projections -> dense triangular scores -> wave select
  relproj2<<<dim3(RKS, M / 128, 2), blk, 0, stream>>>(rel, Wqr, Wkr, partq, partk, M);
  relreduce<<<(M * DREL / 4 + 255) / 256, blk, 0, stream>>>(partq, partk, qrel, krel, M * DREL / 4);
  relscore<<<dim3(Lq / 128, Lq / 128, Bb), blk, 0, stream>>>(qrel, krel, Sbuf);
  relselect<<<M / 4, blk, 0, stream>>>(Sbuf, maskb);

  // bf16 conversions (overwrite Sbuf region only after relselect has consumed it)
  conv_bf16<<<(hsN8 + 255) / 256, blk, 0, stream>>>(hs, hsb, hsN8, 1.0f);
  conv_bf16_w4<<<dim3(ND / 8 / 256, 4), blk, 0, stream>>>(Wq, Wk, Wv, Wo, Wqkvo, QSCALE);

  // fused QKV projection: 128x256 tile, BK=32, true 2 blocks/CU (768 blocks)
  gemmP<4, true><<<dim3((M / 128) * (3 * Dm / 256)), dim3(512), 0, stream>>>(
      hsb, Wqkvo, qkvb, M, 3 * Dm, Dm);

  // flash attention v3
  attn_flash3<<<dim3(Lq / ATQ, Hh, Bb), dim3(512), 0, stream>>>(qkvb, maskb, ctxb);

  // O projection -> fp32 out: 128x256 tile -> grid = 32*8 = 256 blocks
  gemmP<4, false><<<dim3((M / 128) * (Dm / 256)), dim3(512), 0, stream>>>(
      ctxb, Wqkvo + (size_t)3 * ND, out, M, Dm, Dm);
}